// Round 1
// baseline (1824.114 us; speedup 1.0000x reference)
//
#include <hip/hip_runtime.h>

#define B_ 4
#define T_ 4096
#define D_ 512
#define H_ 8
#define DH_ 64
#define NH_ 4
#define NB_ 64            // n_buckets = T/BUCKET
#define BH_ (B_*H_)       // 32
#define CHUNKS_ (NH_*NB_) // 256
#define NTICK_ (NH_*T_)   // 16384
#define M_ (B_*T_)        // 16384
#define FFN_ 2048

// ---------- bf16 helpers (round-to-nearest-even) ----------
__device__ __forceinline__ unsigned short f2bf(float x) {
  unsigned int u = __float_as_uint(x);
  return (unsigned short)((u + 0x7FFFu + ((u >> 16) & 1u)) >> 16);
}
__device__ __forceinline__ float bf2f(unsigned short s) {
  return __uint_as_float(((unsigned int)s) << 16);
}
__device__ __forceinline__ float bflo(unsigned int u) { return __uint_as_float(u << 16); }
__device__ __forceinline__ float bfhi(unsigned int u) { return __uint_as_float(u & 0xFFFF0000u); }

// ---------- generic fp32 GEMM: C = op(A@B + bias) (+ resid) ----------
// A: MxK row-major, B: KxN row-major. BM=BN=128, BK=16, 256 thr, 8x8 microtile.
template<bool HAS_BIAS, bool RELU, bool HAS_RESID>
__global__ __launch_bounds__(256) void gemm_f32(
    const float* __restrict__ A, const float* __restrict__ Bm,
    const float* __restrict__ bias, const float* __restrict__ resid,
    float* __restrict__ C, int M, int N, int K)
{
  __shared__ __align__(16) float As[16][132];   // transposed: As[k][m]
  __shared__ __align__(16) float Bs[16][132];
  const int tid = threadIdx.x;
  const int tx = tid & 15, ty = tid >> 4;
  const int m0 = blockIdx.y * 128, n0 = blockIdx.x * 128;
  float acc[8][8];
#pragma unroll
  for (int i = 0; i < 8; ++i)
#pragma unroll
    for (int j = 0; j < 8; ++j) acc[i][j] = 0.f;

  for (int k0 = 0; k0 < K; k0 += 16) {
#pragma unroll
    for (int l = 0; l < 2; ++l) {
      const int idx = tid + l * 256;      // 0..511 float4s
      const int row = idx >> 2;           // 0..127
      const int kq = (idx & 3) << 2;      // 0,4,8,12
      const float4 a = *(const float4*)&A[(size_t)(m0 + row) * K + k0 + kq];
      As[kq + 0][row] = a.x; As[kq + 1][row] = a.y;
      As[kq + 2][row] = a.z; As[kq + 3][row] = a.w;
    }
#pragma unroll
    for (int l = 0; l < 2; ++l) {
      const int idx = tid + l * 256;
      const int kr = idx >> 5;            // 0..15
      const int c4 = (idx & 31) << 2;     // 0..124
      *(float4*)&Bs[kr][c4] = *(const float4*)&Bm[(size_t)(k0 + kr) * N + n0 + c4];
    }
    __syncthreads();
#pragma unroll
    for (int kk = 0; kk < 16; ++kk) {
      float a[8], b[8];
      *(float4*)&a[0] = *(const float4*)&As[kk][ty * 8];
      *(float4*)&a[4] = *(const float4*)&As[kk][ty * 8 + 4];
      *(float4*)&b[0] = *(const float4*)&Bs[kk][tx * 8];
      *(float4*)&b[4] = *(const float4*)&Bs[kk][tx * 8 + 4];
#pragma unroll
      for (int i = 0; i < 8; ++i)
#pragma unroll
        for (int j = 0; j < 8; ++j)
          acc[i][j] = fmaf(a[i], b[j], acc[i][j]);
    }
    __syncthreads();
  }
#pragma unroll
  for (int i = 0; i < 8; ++i) {
    const size_t m = (size_t)m0 + ty * 8 + i;
    const size_t cb = m * N + n0 + tx * 8;
    float vout[8];
#pragma unroll
    for (int j = 0; j < 8; ++j) {
      float val = acc[i][j];
      if (HAS_BIAS) val += bias[n0 + tx * 8 + j];
      if (RELU) val = fmaxf(val, 0.f);
      vout[j] = val;
    }
    if (HAS_RESID) {
      const float4 r0 = *(const float4*)&resid[cb];
      const float4 r1 = *(const float4*)&resid[cb + 4];
      vout[0] += r0.x; vout[1] += r0.y; vout[2] += r0.z; vout[3] += r0.w;
      vout[4] += r1.x; vout[5] += r1.y; vout[6] += r1.z; vout[7] += r1.w;
    }
    *(float4*)&C[cb]     = make_float4(vout[0], vout[1], vout[2], vout[3]);
    *(float4*)&C[cb + 4] = make_float4(vout[4], vout[5], vout[6], vout[7]);
  }
}

// ---------- per-(bh,t) inverse key norm: 1/(||qk_head_row|| + 1e-6) ----------
__global__ __launch_bounds__(256) void invnorm_kernel(
    const float* __restrict__ qk, float* __restrict__ invn)
{
  const int gid = blockIdx.x * 4 + (threadIdx.x >> 6);
  const int lane = threadIdx.x & 63;
  const int bh = gid >> 12, t = gid & (T_ - 1);
  const int b = bh >> 3, hd = bh & 7;
  const float x = qk[((size_t)b * T_ + t) * D_ + hd * DH_ + lane];
  float s = x * x;
#pragma unroll
  for (int m = 32; m >= 1; m >>= 1) s += __shfl_xor(s, m);
  if (lane == 0) invn[gid] = 1.0f / (sqrtf(s) + 1e-6f);
}

// ---------- LSH hashing: argmax over [rv,-rv] (first-occurrence ties) ----------
__global__ __launch_bounds__(256) void hash_kernel(
    const float* __restrict__ qk, const float* __restrict__ rot,
    int* __restrict__ buckets)
{
  __shared__ float rs[64 * NH_ * 32];   // rot[f][h][i]
  for (int i = threadIdx.x; i < 64 * NH_ * 32; i += 256) rs[i] = rot[i];
  __syncthreads();
  const int bh = blockIdx.x;
  const int b = bh >> 3, hd = bh & 7;
  const int wave = threadIdx.x >> 6, lane = threadIdx.x & 63;
  const int t0 = blockIdx.y * 64 + wave * 16;
  for (int tt = 0; tt < 16; ++tt) {
    const int t = t0 + tt;
    const float q = qk[((size_t)b * T_ + t) * D_ + hd * DH_ + lane];
#pragma unroll
    for (int pass = 0; pass < 2; ++pass) {
      const int h = pass * 2 + (lane >> 5);
      const int i = lane & 31;
      float acc = 0.f;
#pragma unroll
      for (int f = 0; f < 64; ++f)
        acc = fmaf(__shfl(q, f), rs[f * (NH_ * 32) + h * 32 + i], acc);
      float v = acc; int idx = i;
      if (-acc > acc) { v = -acc; idx = 32 + i; }   // tie keeps +rv (smaller idx)
#pragma unroll
      for (int m = 16; m >= 1; m >>= 1) {
        const float ov = __shfl_xor(v, m);
        const int oi = __shfl_xor(idx, m);
        if (ov > v || (ov == v && oi < idx)) { v = ov; idx = oi; }
      }
      if ((lane & 31) == 0)
        buckets[((size_t)bh * NH_ + h) * T_ + t] = idx + h * NB_;
    }
  }
}

// ---------- per-bh bucket histogram + exclusive scan ----------
__global__ __launch_bounds__(256) void hist_kernel(
    const int* __restrict__ buckets, int* __restrict__ bstart)
{
  __shared__ int bins[256];
  const int bh = blockIdx.x;
  bins[threadIdx.x] = 0;
  __syncthreads();
  for (int e = threadIdx.x; e < NTICK_; e += 256)
    atomicAdd(&bins[buckets[(size_t)bh * NTICK_ + e]], 1);
  __syncthreads();
  if (threadIdx.x == 0) {
    int run = 0;
    for (int i = 0; i < 256; ++i) { const int c = bins[i]; bins[i] = run; run += c; }
  }
  __syncthreads();
  bstart[bh * 256 + threadIdx.x] = bins[threadIdx.x];
}

// ---------- stable compaction: sticker = argsort(bucket*T + t) ----------
__global__ __launch_bounds__(64) void compact_kernel(
    const int* __restrict__ buckets, const int* __restrict__ bstart,
    int* __restrict__ sticker)
{
  const int bucket = blockIdx.x, bh = blockIdx.y;
  const int h = bucket >> 6;
  const int lane = threadIdx.x;
  int base = bstart[bh * 256 + bucket];
  const int* bk = buckets + (size_t)bh * NTICK_ + (size_t)h * T_;
  for (int it = 0; it < 64; ++it) {
    const int t = it * 64 + lane;
    const bool m = (bk[t] == bucket);
    const unsigned long long bal = __ballot(m);
    if (m) {
      const int pos = base + __popcll(bal & ((1ull << lane) - 1ull));
      sticker[(size_t)bh * NTICK_ + pos] = h * T_ + t;
    }
    base += __popcll(bal);
  }
}

// ---------- chunked LSH attention ----------
__global__ __launch_bounds__(256) void attn_kernel(
    const float* __restrict__ qk, const float* __restrict__ v,
    const int* __restrict__ sticker, const float* __restrict__ invn,
    float* __restrict__ orows, float* __restrict__ logits)
{
  __shared__ __align__(16) unsigned short Rs[128][66]; // raw qk rows (bf16)
  __shared__ __align__(16) unsigned short Vs[128][64]; // v rows (bf16)
  __shared__ __align__(16) unsigned short Ps[64][130]; // softmax probs (bf16)
  __shared__ int tks[128];
  __shared__ float invs[128];

  const int c = blockIdx.x;        // chunk
  const int bh = blockIdx.y;
  const int b = bh >> 3, hd = bh & 7;
  const int tid = threadIdx.x;
  const int hr = c >> 6;           // hash round of queries

  if (tid < 128) {
    const int sc = (tid < 64) ? c : ((c + CHUNKS_ - 1) & (CHUNKS_ - 1));
    const int tick = sticker[(size_t)bh * NTICK_ + sc * 64 + (tid & 63)];
    const int t = tick & (T_ - 1);
    tks[tid] = t;
    invs[tid] = invn[bh * T_ + t];
  }
  __syncthreads();

#pragma unroll
  for (int l = 0; l < 8; ++l) {
    const int idx = tid + l * 256;
    const int row = idx >> 4;
    const int f4 = (idx & 15) << 2;
    const size_t base = ((size_t)b * T_ + tks[row]) * D_ + hd * DH_ + f4;
    const float4 a = *(const float4*)&qk[base];
    Rs[row][f4 + 0] = f2bf(a.x); Rs[row][f4 + 1] = f2bf(a.y);
    Rs[row][f4 + 2] = f2bf(a.z); Rs[row][f4 + 3] = f2bf(a.w);
    const float4 w = *(const float4*)&v[base];
    Vs[row][f4 + 0] = f2bf(w.x); Vs[row][f4 + 1] = f2bf(w.y);
    Vs[row][f4 + 2] = f2bf(w.z); Vs[row][f4 + 3] = f2bf(w.w);
  }
  __syncthreads();

  // --- dots (4 rows x 8 keys per thread) + mask + softmax ---
  {
    const int rg = tid >> 4, kg = tid & 15;
    const int r0 = rg * 4, j0 = kg * 8;
    float acc[4][8];
#pragma unroll
    for (int i = 0; i < 4; ++i)
#pragma unroll
      for (int j = 0; j < 8; ++j) acc[i][j] = 0.f;

    for (int k2 = 0; k2 < 32; ++k2) {
      float qa0[4], qa1[4];
#pragma unroll
      for (int i = 0; i < 4; ++i) {
        const unsigned int u = *(const unsigned int*)&Rs[r0 + i][k2 * 2];
        qa0[i] = bflo(u); qa1[i] = bfhi(u);
      }
#pragma unroll
      for (int j = 0; j < 8; ++j) {
        const unsigned int u = *(const unsigned int*)&Rs[j0 + j][k2 * 2];
        const float kb0 = bflo(u), kb1 = bfhi(u);
#pragma unroll
        for (int i = 0; i < 4; ++i)
          acc[i][j] = fmaf(qa1[i], kb1, fmaf(qa0[i], kb0, acc[i][j]));
      }
    }
    int tq[4];
#pragma unroll
    for (int i = 0; i < 4; ++i) tq[i] = tks[r0 + i];
    int tkj[8]; float iv[8];
#pragma unroll
    for (int j = 0; j < 8; ++j) { tkj[j] = tks[j0 + j]; iv[j] = invs[j0 + j] * 0.125f; }

#pragma unroll
    for (int i = 0; i < 4; ++i) {
      float mx = -3.0e38f;
#pragma unroll
      for (int j = 0; j < 8; ++j) {
        float d = acc[i][j] * iv[j];
        if (tq[i] == tkj[j]) d = -5.0e4f;
        acc[i][j] = d;
        mx = fmaxf(mx, d);
      }
#pragma unroll
      for (int msk = 1; msk < 16; msk <<= 1) mx = fmaxf(mx, __shfl_xor(mx, msk));
      float s = 0.f;
#pragma unroll
      for (int j = 0; j < 8; ++j) s += __expf(acc[i][j] - mx);
#pragma unroll
      for (int msk = 1; msk < 16; msk <<= 1) s += __shfl_xor(s, msk);
      const float lse = mx + __logf(s);
#pragma unroll
      for (int j = 0; j < 8; ++j)
        Ps[r0 + i][j0 + j] = f2bf(__expf(acc[i][j] - lse));
      if (kg == 0)
        logits[((size_t)bh * NH_ + hr) * T_ + tq[i]] = lse;
    }
  }
  __syncthreads();

  // --- PV: o[r][d0..d0+15] = sum_j P[r][j] * V[j][d] ---
  {
    const int r = tid >> 2, qd = tid & 3;
    const int d0 = qd * 16;
    float o[16];
#pragma unroll
    for (int d = 0; d < 16; ++d) o[d] = 0.f;
#pragma unroll 4
    for (int j = 0; j < 128; ++j) {
      const float p = bf2f(Ps[r][j]);
#pragma unroll
      for (int dq = 0; dq < 4; ++dq) {
        const uint2 w = *(const uint2*)&Vs[j][d0 + dq * 4];
        o[dq * 4 + 0] = fmaf(p, bflo(w.x), o[dq * 4 + 0]);
        o[dq * 4 + 1] = fmaf(p, bfhi(w.x), o[dq * 4 + 1]);
        o[dq * 4 + 2] = fmaf(p, bflo(w.y), o[dq * 4 + 2]);
        o[dq * 4 + 3] = fmaf(p, bfhi(w.y), o[dq * 4 + 3]);
      }
    }
    const size_t ob = (((size_t)bh * NH_ + hr) * T_ + tks[r]) * DH_ + d0;
#pragma unroll
    for (int x4 = 0; x4 < 4; ++x4)
      *(float4*)&orows[ob + x4 * 4] =
          make_float4(o[x4 * 4], o[x4 * 4 + 1], o[x4 * 4 + 2], o[x4 * 4 + 3]);
  }
}

// ---------- combine hash rounds: softmax over per-round lse ----------
__global__ __launch_bounds__(256) void combine_kernel(
    const float* __restrict__ orows, const float* __restrict__ logits,
    float* __restrict__ ocomb)
{
  const int gid = blockIdx.x * 4 + (threadIdx.x >> 6);
  const int lane = threadIdx.x & 63;
  const int bh = gid >> 12, t = gid & (T_ - 1);
  const int b = bh >> 3, hd = bh & 7;
  const size_t lb = (size_t)bh * NH_ * T_ + t;
  const float l0 = logits[lb];
  const float l1 = logits[lb + T_];
  const float l2 = logits[lb + 2 * T_];
  const float l3 = logits[lb + 3 * T_];
  const float m = fmaxf(fmaxf(l0, l1), fmaxf(l2, l3));
  const float w0 = __expf(l0 - m), w1 = __expf(l1 - m);
  const float w2 = __expf(l2 - m), w3 = __expf(l3 - m);
  const float inv = 1.f / (w0 + w1 + w2 + w3);
  const size_t rb = ((size_t)bh * NH_ * T_ + t) * DH_ + lane;
  const size_t step = (size_t)T_ * DH_;
  const float o = w0 * orows[rb] + w1 * orows[rb + step]
                + w2 * orows[rb + 2 * step] + w3 * orows[rb + 3 * step];
  ocomb[((size_t)b * T_ + t) * D_ + hd * DH_ + lane] = o * inv;
}

// ---------- LayerNorm ----------
__global__ __launch_bounds__(256) void ln_kernel(
    const float* __restrict__ y, const float* __restrict__ gamma,
    const float* __restrict__ beta, float* __restrict__ out)
{
  const int row = blockIdx.x * 4 + (threadIdx.x >> 6);
  const int lane = threadIdx.x & 63;
  const size_t base = (size_t)row * D_ + lane * 8;
  float x[8];
  *(float4*)&x[0] = *(const float4*)&y[base];
  *(float4*)&x[4] = *(const float4*)&y[base + 4];
  float s = 0.f;
#pragma unroll
  for (int i = 0; i < 8; ++i) s += x[i];
#pragma unroll
  for (int m = 32; m >= 1; m >>= 1) s += __shfl_xor(s, m);
  const float mu = s * (1.f / D_);
  float vs = 0.f;
#pragma unroll
  for (int i = 0; i < 8; ++i) { const float d = x[i] - mu; vs += d * d; }
#pragma unroll
  for (int m = 32; m >= 1; m >>= 1) vs += __shfl_xor(vs, m);
  const float rstd = rsqrtf(vs * (1.f / D_) + 1e-6f);
  float g[8], bt[8];
  *(float4*)&g[0]  = *(const float4*)&gamma[lane * 8];
  *(float4*)&g[4]  = *(const float4*)&gamma[lane * 8 + 4];
  *(float4*)&bt[0] = *(const float4*)&beta[lane * 8];
  *(float4*)&bt[4] = *(const float4*)&beta[lane * 8 + 4];
  float o[8];
#pragma unroll
  for (int i = 0; i < 8; ++i) o[i] = (x[i] - mu) * rstd * g[i] + bt[i];
  *(float4*)&out[base]     = make_float4(o[0], o[1], o[2], o[3]);
  *(float4*)&out[base + 4] = make_float4(o[4], o[5], o[6], o[7]);
}

extern "C" void kernel_launch(void* const* d_in, const int* in_sizes, int n_in,
                              void* d_out, int out_size, void* d_ws, size_t ws_size,
                              hipStream_t stream) {
  (void)in_sizes; (void)n_in; (void)out_size; (void)ws_size;
  const float* src   = (const float*)d_in[0];
  const float* Wqk   = (const float*)d_in[1];
  const float* Wv    = (const float*)d_in[2];
  const float* Wout  = (const float*)d_in[3];
  const float* bout  = (const float*)d_in[4];
  const float* W1    = (const float*)d_in[5];
  const float* b1    = (const float*)d_in[6];
  const float* W2    = (const float*)d_in[7];
  const float* b2    = (const float*)d_in[8];
  const float* gamma = (const float*)d_in[9];
  const float* beta  = (const float*)d_in[10];
  const float* rot   = (const float*)d_in[11];
  float* out = (float*)d_out;

  char* ws = (char*)d_ws;
  const size_t SZ32 = (size_t)M_ * D_ * 4;                 // 32 MB
  float* qk    = (float*)(ws);                             // -> reused as x
  float* vbuf  = (float*)(ws + SZ32);                      // -> ocomb -> y
  float* orows = (float*)(ws + 2 * SZ32);                  // 128 MB -> hidden
  char* p = ws + 2 * SZ32 + (size_t)BH_ * NH_ * T_ * DH_ * 4;
  float* logits  = (float*)p; p += (size_t)BH_ * NH_ * T_ * 4;
  int*   buckets = (int*)p;   p += (size_t)BH_ * NH_ * T_ * 4;
  int*   sticker = (int*)p;   p += (size_t)BH_ * NTICK_ * 4;
  int*   bstart  = (int*)p;   p += (size_t)BH_ * 256 * 4;
  float* invn    = (float*)p; p += (size_t)BH_ * T_ * 4;
  float* x = qk;          // after attention, qk region becomes x
  float* ocomb = vbuf;    // after attention, v region becomes combined o
  float* hidden = orows;  // after combine, o_rounds region becomes FFN hidden
  float* ybuf = vbuf;     // after Wout GEMM, becomes y

  // 1-2: projections (fp32 — hashing is sensitive to qk precision)
  gemm_f32<false, false, false><<<dim3(4, 128), 256, 0, stream>>>(
      src, Wqk, nullptr, nullptr, qk, M_, D_, D_);
  gemm_f32<false, false, false><<<dim3(4, 128), 256, 0, stream>>>(
      src, Wv, nullptr, nullptr, vbuf, M_, D_, D_);
  // 3: key inverse norms
  invnorm_kernel<<<BH_ * T_ / 4, 256, 0, stream>>>(qk, invn);
  // 4: LSH buckets
  hash_kernel<<<dim3(BH_, T_ / 64), 256, 0, stream>>>(qk, rot, buckets);
  // 5-6: counting sort (histogram+scan, then stable compaction)
  hist_kernel<<<BH_, 256, 0, stream>>>(buckets, bstart);
  compact_kernel<<<dim3(256, BH_), 64, 0, stream>>>(buckets, bstart, sticker);
  // 7: chunked attention (scatters o and lse back to (h, t))
  attn_kernel<<<dim3(CHUNKS_, BH_), 256, 0, stream>>>(
      qk, vbuf, sticker, invn, orows, logits);
  // 8: combine 4 hash rounds
  combine_kernel<<<BH_ * T_ / 4, 256, 0, stream>>>(orows, logits, ocomb);
  // 9: out projection + residual
  gemm_f32<true, false, true><<<dim3(4, 128), 256, 0, stream>>>(
      ocomb, Wout, bout, src, x, M_, D_, D_);
  // 10: FFN1 (relu)
  gemm_f32<true, true, false><<<dim3(16, 128), 256, 0, stream>>>(
      x, W1, b1, nullptr, hidden, M_, FFN_, D_);
  // 11: FFN2 + residual
  gemm_f32<true, false, true><<<dim3(4, 128), 256, 0, stream>>>(
      hidden, W2, b2, x, ybuf, M_, D_, FFN_);
  // 12: LayerNorm
  ln_kernel<<<M_ / 4, 256, 0, stream>>>(ybuf, gamma, beta, out);
}

// Round 2
// 972.607 us; speedup vs baseline: 1.8755x; 1.8755x over previous
//
#include <hip/hip_runtime.h>

#define B_ 4
#define T_ 4096
#define D_ 512
#define H_ 8
#define DH_ 64
#define NH_ 4
#define NB_ 64            // n_buckets = T/BUCKET
#define BH_ (B_*H_)       // 32
#define CHUNKS_ (NH_*NB_) // 256
#define NTICK_ (NH_*T_)   // 16384
#define M_ (B_*T_)        // 16384
#define FFN_ 2048

typedef __attribute__((ext_vector_type(8))) short bf16x8;
typedef __attribute__((ext_vector_type(4))) float f32x4;

// ---------- bf16 helpers (round-to-nearest-even) ----------
__device__ __forceinline__ unsigned short f2bf(float x) {
  unsigned int u = __float_as_uint(x);
  return (unsigned short)((u + 0x7FFFu + ((u >> 16) & 1u)) >> 16);
}
__device__ __forceinline__ float bf2f(unsigned short s) {
  return __uint_as_float(((unsigned int)s) << 16);
}
__device__ __forceinline__ float bflo(unsigned int u) { return __uint_as_float(u << 16); }
__device__ __forceinline__ float bfhi(unsigned int u) { return __uint_as_float(u & 0xFFFF0000u); }

// ---------- async global->LDS, 16B per lane ----------
__device__ __forceinline__ void gld_lds16(const void* g, void* l) {
  __builtin_amdgcn_global_load_lds(
      (const __attribute__((address_space(1))) unsigned int*)g,
      (__attribute__((address_space(3))) unsigned int*)l, 16, 0, 0);
}

// ---------- fp32 GEMM (kept for qk only: hash argmax is precision-sensitive) ----------
template<bool HAS_BIAS, bool RELU, bool HAS_RESID>
__global__ __launch_bounds__(256) void gemm_f32(
    const float* __restrict__ A, const float* __restrict__ Bm,
    const float* __restrict__ bias, const float* __restrict__ resid,
    float* __restrict__ C, int M, int N, int K)
{
  __shared__ __align__(16) float As[16][132];   // transposed: As[k][m]
  __shared__ __align__(16) float Bs[16][132];
  const int tid = threadIdx.x;
  const int tx = tid & 15, ty = tid >> 4;
  const int m0 = blockIdx.y * 128, n0 = blockIdx.x * 128;
  float acc[8][8];
#pragma unroll
  for (int i = 0; i < 8; ++i)
#pragma unroll
    for (int j = 0; j < 8; ++j) acc[i][j] = 0.f;

  for (int k0 = 0; k0 < K; k0 += 16) {
#pragma unroll
    for (int l = 0; l < 2; ++l) {
      const int idx = tid + l * 256;
      const int row = idx >> 2;
      const int kq = (idx & 3) << 2;
      const float4 a = *(const float4*)&A[(size_t)(m0 + row) * K + k0 + kq];
      As[kq + 0][row] = a.x; As[kq + 1][row] = a.y;
      As[kq + 2][row] = a.z; As[kq + 3][row] = a.w;
    }
#pragma unroll
    for (int l = 0; l < 2; ++l) {
      const int idx = tid + l * 256;
      const int kr = idx >> 5;
      const int c4 = (idx & 31) << 2;
      *(float4*)&Bs[kr][c4] = *(const float4*)&Bm[(size_t)(k0 + kr) * N + n0 + c4];
    }
    __syncthreads();
#pragma unroll
    for (int kk = 0; kk < 16; ++kk) {
      float a[8], b[8];
      *(float4*)&a[0] = *(const float4*)&As[kk][ty * 8];
      *(float4*)&a[4] = *(const float4*)&As[kk][ty * 8 + 4];
      *(float4*)&b[0] = *(const float4*)&Bs[kk][tx * 8];
      *(float4*)&b[4] = *(const float4*)&Bs[kk][tx * 8 + 4];
#pragma unroll
      for (int i = 0; i < 8; ++i)
#pragma unroll
        for (int j = 0; j < 8; ++j)
          acc[i][j] = fmaf(a[i], b[j], acc[i][j]);
    }
    __syncthreads();
  }
#pragma unroll
  for (int i = 0; i < 8; ++i) {
    const size_t m = (size_t)m0 + ty * 8 + i;
    const size_t cb = m * N + n0 + tx * 8;
    float vout[8];
#pragma unroll
    for (int j = 0; j < 8; ++j) {
      float val = acc[i][j];
      if (HAS_BIAS) val += bias[n0 + tx * 8 + j];
      if (RELU) val = fmaxf(val, 0.f);
      vout[j] = val;
    }
    if (HAS_RESID) {
      const float4 r0 = *(const float4*)&resid[cb];
      const float4 r1 = *(const float4*)&resid[cb + 4];
      vout[0] += r0.x; vout[1] += r0.y; vout[2] += r0.z; vout[3] += r0.w;
      vout[4] += r1.x; vout[5] += r1.y; vout[6] += r1.z; vout[7] += r1.w;
    }
    *(float4*)&C[cb]     = make_float4(vout[0], vout[1], vout[2], vout[3]);
    *(float4*)&C[cb + 4] = make_float4(vout[4], vout[5], vout[6], vout[7]);
  }
}

// ---------- bf16 MFMA GEMM (m97 structure): C = op(A @ BT^T) ----------
// A: MxK bf16 row-major. BT: NxK bf16 row-major (pre-transposed B).
// OUT_MODE: 0 = fp32 out, 1 = bf16 out, 2 = both.
template<int OUT_MODE, bool HAS_BIAS, bool RELU, bool HAS_RESID>
__global__ __launch_bounds__(256) void gemm_bf16(
    const unsigned short* __restrict__ A, const unsigned short* __restrict__ BT,
    const float* __restrict__ bias, const float* __restrict__ resid,
    float* __restrict__ Cf, unsigned short* __restrict__ Cb,
    int M, int N, int K)
{
  __shared__ __align__(16) unsigned short As[128 * 64];   // [row][k] linear
  __shared__ __align__(16) unsigned short Bs[128 * 64];   // [col][k] linear
  const int tid = threadIdx.x;
  const int lane = tid & 63;
  const int w = tid >> 6;
  const int wm = (w >> 1) * 64, wn = (w & 1) * 64;
  const int m0 = blockIdx.y * 128, n0 = blockIdx.x * 128;

  f32x4 acc[4][4];
#pragma unroll
  for (int i = 0; i < 4; ++i)
#pragma unroll
    for (int j = 0; j < 4; ++j) acc[i][j] = (f32x4){0.f, 0.f, 0.f, 0.f};

  const int srow = tid >> 3;          // 0..31 within a 32-row chunk
  const int skc  = (tid & 7) * 8;     // k element offset (16B granules)

  for (int k0 = 0; k0 < K; k0 += 64) {
#pragma unroll
    for (int ci = 0; ci < 4; ++ci) {
      const int row = ci * 32 + srow;
      gld_lds16(&A [(size_t)(m0 + row) * K + k0 + skc], &As[ci * 2048 + tid * 8]);
      gld_lds16(&BT[(size_t)(n0 + row) * K + k0 + skc], &Bs[ci * 2048 + tid * 8]);
    }
    __syncthreads();
#pragma unroll
    for (int kk = 0; kk < 64; kk += 32) {
      bf16x8 af[4], bfr[4];
#pragma unroll
      for (int i = 0; i < 4; ++i)
        af[i] = *(const bf16x8*)&As[(wm + i * 16 + (lane & 15)) * 64 + kk + (lane >> 4) * 8];
#pragma unroll
      for (int j = 0; j < 4; ++j)
        bfr[j] = *(const bf16x8*)&Bs[(wn + j * 16 + (lane & 15)) * 64 + kk + (lane >> 4) * 8];
#pragma unroll
      for (int i = 0; i < 4; ++i)
#pragma unroll
        for (int j = 0; j < 4; ++j)
          acc[i][j] = __builtin_amdgcn_mfma_f32_16x16x32_bf16(af[i], bfr[j], acc[i][j], 0, 0, 0);
    }
    __syncthreads();
  }

  // epilogue: C/D layout col=lane&15, row=(lane>>4)*4+reg  [m89/m91]
#pragma unroll
  for (int i = 0; i < 4; ++i) {
#pragma unroll
    for (int j = 0; j < 4; ++j) {
      const int col = n0 + wn + j * 16 + (lane & 15);
#pragma unroll
      for (int r = 0; r < 4; ++r) {
        const int row = m0 + wm + i * 16 + (lane >> 4) * 4 + r;
        float val = acc[i][j][r];
        if constexpr (HAS_BIAS) val += bias[col];
        if constexpr (RELU) val = fmaxf(val, 0.f);
        if constexpr (HAS_RESID) val += resid[(size_t)row * N + col];
        if constexpr (OUT_MODE == 0 || OUT_MODE == 2) Cf[(size_t)row * N + col] = val;
        if constexpr (OUT_MODE == 1 || OUT_MODE == 2) Cb[(size_t)row * N + col] = f2bf(val);
      }
    }
  }
}

// ---------- fp32 -> bf16 elementwise (8 elems/thread) ----------
__global__ __launch_bounds__(256) void cvt_f2bf(
    const float* __restrict__ in, unsigned short* __restrict__ out, int n8)
{
  const int i = blockIdx.x * 256 + threadIdx.x;
  if (i >= n8) return;
  const size_t b = (size_t)i * 8;
  const float4 v0 = *(const float4*)&in[b];
  const float4 v1 = *(const float4*)&in[b + 4];
  unsigned short o[8] = {f2bf(v0.x), f2bf(v0.y), f2bf(v0.z), f2bf(v0.w),
                         f2bf(v1.x), f2bf(v1.y), f2bf(v1.z), f2bf(v1.w)};
  *(uint4*)&out[b] = *(const uint4*)&o[0];
}

// ---------- transpose + convert: W (KxN f32) -> WT (NxK bf16) ----------
__global__ __launch_bounds__(256) void transpose_f2bf(
    const float* __restrict__ W, unsigned short* __restrict__ WT, int K, int N)
{
  __shared__ float tile[32][33];
  const int k0 = blockIdx.y * 32, n0 = blockIdx.x * 32;
  const int tx = threadIdx.x & 31, ty = threadIdx.x >> 5;   // 32 x 8
#pragma unroll
  for (int r = 0; r < 32; r += 8)
    tile[ty + r][tx] = W[(size_t)(k0 + ty + r) * N + n0 + tx];
  __syncthreads();
#pragma unroll
  for (int r = 0; r < 32; r += 8)
    WT[(size_t)(n0 + ty + r) * K + k0 + tx] = f2bf(tile[tx][ty + r]);
}

// ---------- per-(bh,t) inverse key norm ----------
__global__ __launch_bounds__(256) void invnorm_kernel(
    const float* __restrict__ qk, float* __restrict__ invn)
{
  const int gid = blockIdx.x * 4 + (threadIdx.x >> 6);
  const int lane = threadIdx.x & 63;
  const int bh = gid >> 12, t = gid & (T_ - 1);
  const int b = bh >> 3, hd = bh & 7;
  const float x = qk[((size_t)b * T_ + t) * D_ + hd * DH_ + lane];
  float s = x * x;
#pragma unroll
  for (int m = 32; m >= 1; m >>= 1) s += __shfl_xor(s, m);
  if (lane == 0) invn[gid] = 1.0f / (sqrtf(s) + 1e-6f);
}

// ---------- LSH hashing: argmax over [rv,-rv] ----------
__global__ __launch_bounds__(256) void hash_kernel(
    const float* __restrict__ qk, const float* __restrict__ rot,
    int* __restrict__ buckets)
{
  __shared__ float rs[64 * NH_ * 32];   // rot[f][h][i]
  for (int i = threadIdx.x; i < 64 * NH_ * 32; i += 256) rs[i] = rot[i];
  __syncthreads();
  const int bh = blockIdx.x;
  const int b = bh >> 3, hd = bh & 7;
  const int wave = threadIdx.x >> 6, lane = threadIdx.x & 63;
  const int t0 = blockIdx.y * 64 + wave * 16;
  for (int tt = 0; tt < 16; ++tt) {
    const int t = t0 + tt;
    const float q = qk[((size_t)b * T_ + t) * D_ + hd * DH_ + lane];
#pragma unroll
    for (int pass = 0; pass < 2; ++pass) {
      const int h = pass * 2 + (lane >> 5);
      const int i = lane & 31;
      float acc = 0.f;
#pragma unroll
      for (int f = 0; f < 64; ++f)
        acc = fmaf(__shfl(q, f), rs[f * (NH_ * 32) + h * 32 + i], acc);
      float v = acc; int idx = i;
      if (-acc > acc) { v = -acc; idx = 32 + i; }
#pragma unroll
      for (int m = 16; m >= 1; m >>= 1) {
        const float ov = __shfl_xor(v, m);
        const int oi = __shfl_xor(idx, m);
        if (ov > v || (ov == v && oi < idx)) { v = ov; idx = oi; }
      }
      if ((lane & 31) == 0)
        buckets[((size_t)bh * NH_ + h) * T_ + t] = idx + h * NB_;
    }
  }
}

// ---------- per-bh bucket histogram + exclusive scan ----------
__global__ __launch_bounds__(256) void hist_kernel(
    const int* __restrict__ buckets, int* __restrict__ bstart)
{
  __shared__ int bins[256];
  const int bh = blockIdx.x;
  bins[threadIdx.x] = 0;
  __syncthreads();
  for (int e = threadIdx.x; e < NTICK_; e += 256)
    atomicAdd(&bins[buckets[(size_t)bh * NTICK_ + e]], 1);
  __syncthreads();
  if (threadIdx.x == 0) {
    int run = 0;
    for (int i = 0; i < 256; ++i) { const int c = bins[i]; bins[i] = run; run += c; }
  }
  __syncthreads();
  bstart[bh * 256 + threadIdx.x] = bins[threadIdx.x];
}

// ---------- stable compaction ----------
__global__ __launch_bounds__(64) void compact_kernel(
    const int* __restrict__ buckets, const int* __restrict__ bstart,
    int* __restrict__ sticker)
{
  const int bucket = blockIdx.x, bh = blockIdx.y;
  const int h = bucket >> 6;
  const int lane = threadIdx.x;
  int base = bstart[bh * 256 + bucket];
  const int* bk = buckets + (size_t)bh * NTICK_ + (size_t)h * T_;
  for (int it = 0; it < 64; ++it) {
    const int t = it * 64 + lane;
    const bool m = (bk[t] == bucket);
    const unsigned long long bal = __ballot(m);
    if (m) {
      const int pos = base + __popcll(bal & ((1ull << lane) - 1ull));
      sticker[(size_t)bh * NTICK_ + pos] = h * T_ + t;
    }
    base += __popcll(bal);
  }
}

// ---------- chunked LSH attention (qk fp32, v bf16, o bf16) ----------
__global__ __launch_bounds__(256) void attn_kernel(
    const float* __restrict__ qk, const unsigned short* __restrict__ vb,
    const int* __restrict__ sticker, const float* __restrict__ invn,
    unsigned short* __restrict__ orowsb, float* __restrict__ logits)
{
  __shared__ __align__(16) unsigned short Rs[128][66]; // raw qk rows (bf16)
  __shared__ __align__(16) unsigned short Vs[128][64]; // v rows (bf16)
  __shared__ __align__(16) unsigned short Ps[64][130]; // softmax probs (bf16)
  __shared__ int tks[128];
  __shared__ float invs[128];

  const int c = blockIdx.x;
  const int bh = blockIdx.y;
  const int b = bh >> 3, hd = bh & 7;
  const int tid = threadIdx.x;
  const int hr = c >> 6;

  if (tid < 128) {
    const int sc = (tid < 64) ? c : ((c + CHUNKS_ - 1) & (CHUNKS_ - 1));
    const int tick = sticker[(size_t)bh * NTICK_ + sc * 64 + (tid & 63)];
    const int t = tick & (T_ - 1);
    tks[tid] = t;
    invs[tid] = invn[bh * T_ + t];
  }
  __syncthreads();

  // stage qk rows (fp32 -> bf16), 128 rows x 64
#pragma unroll
  for (int l = 0; l < 8; ++l) {
    const int idx = tid + l * 256;
    const int row = idx >> 4;
    const int f4 = (idx & 15) << 2;
    const float4 a = *(const float4*)&qk[((size_t)b * T_ + tks[row]) * D_ + hd * DH_ + f4];
    Rs[row][f4 + 0] = f2bf(a.x); Rs[row][f4 + 1] = f2bf(a.y);
    Rs[row][f4 + 2] = f2bf(a.z); Rs[row][f4 + 3] = f2bf(a.w);
  }
  // stage v rows (already bf16), 128 rows x 64
#pragma unroll
  for (int l = 0; l < 4; ++l) {
    const int idx = tid + l * 256;
    const int row = idx >> 3;
    const int f8 = (idx & 7) * 8;
    *(uint4*)&Vs[row][f8] =
        *(const uint4*)&vb[((size_t)b * T_ + tks[row]) * D_ + hd * DH_ + f8];
  }
  __syncthreads();

  // --- dots (4 rows x 8 keys per thread) + mask + softmax ---
  {
    const int rg = tid >> 4, kg = tid & 15;
    const int r0 = rg * 4, j0 = kg * 8;
    float acc[4][8];
#pragma unroll
    for (int i = 0; i < 4; ++i)
#pragma unroll
      for (int j = 0; j < 8; ++j) acc[i][j] = 0.f;

    for (int k2 = 0; k2 < 32; ++k2) {
      float qa0[4], qa1[4];
#pragma unroll
      for (int i = 0; i < 4; ++i) {
        const unsigned int u = *(const unsigned int*)&Rs[r0 + i][k2 * 2];
        qa0[i] = bflo(u); qa1[i] = bfhi(u);
      }
#pragma unroll
      for (int j = 0; j < 8; ++j) {
        const unsigned int u = *(const unsigned int*)&Rs[j0 + j][k2 * 2];
        const float kb0 = bflo(u), kb1 = bfhi(u);
#pragma unroll
        for (int i = 0; i < 4; ++i)
          acc[i][j] = fmaf(qa1[i], kb1, fmaf(qa0[i], kb0, acc[i][j]));
      }
    }
    int tq[4];
#pragma unroll
    for (int i = 0; i < 4; ++i) tq[i] = tks[r0 + i];
    int tkj[8]; float iv[8];
#pragma unroll
    for (int j = 0; j < 8; ++j) { tkj[j] = tks[j0 + j]; iv[j] = invs[j0 + j] * 0.125f; }

#pragma unroll
    for (int i = 0; i < 4; ++i) {
      float mx = -3.0e38f;
#pragma unroll
      for (int j = 0; j < 8; ++j) {
        float d = acc[i][j] * iv[j];
        if (tq[i] == tkj[j]) d = -5.0e4f;
        acc[i][j] = d;
        mx = fmaxf(mx, d);
      }
#pragma unroll
      for (int msk = 1; msk < 16; msk <<= 1) mx = fmaxf(mx, __shfl_xor(mx, msk));
      float s = 0.f;
#pragma unroll
      for (int j = 0; j < 8; ++j) s += __expf(acc[i][j] - mx);
#pragma unroll
      for (int msk = 1; msk < 16; msk <<= 1) s += __shfl_xor(s, msk);
      const float lse = mx + __logf(s);
#pragma unroll
      for (int j = 0; j < 8; ++j)
        Ps[r0 + i][j0 + j] = f2bf(__expf(acc[i][j] - lse));
      if (kg == 0)
        logits[((size_t)bh * NH_ + hr) * T_ + tq[i]] = lse;
    }
  }
  __syncthreads();

  // --- PV ---
  {
    const int r = tid >> 2, qd = tid & 3;
    const int d0 = qd * 16;
    float o[16];
#pragma unroll
    for (int d = 0; d < 16; ++d) o[d] = 0.f;
#pragma unroll 4
    for (int j = 0; j < 128; ++j) {
      const float p = bf2f(Ps[r][j]);
#pragma unroll
      for (int dq = 0; dq < 4; ++dq) {
        const uint2 w = *(const uint2*)&Vs[j][d0 + dq * 4];
        o[dq * 4 + 0] = fmaf(p, bflo(w.x), o[dq * 4 + 0]);
        o[dq * 4 + 1] = fmaf(p, bfhi(w.x), o[dq * 4 + 1]);
        o[dq * 4 + 2] = fmaf(p, bflo(w.y), o[dq * 4 + 2]);
        o[dq * 4 + 3] = fmaf(p, bfhi(w.y), o[dq * 4 + 3]);
      }
    }
    unsigned short ob16[16];
#pragma unroll
    for (int d = 0; d < 16; ++d) ob16[d] = f2bf(o[d]);
    const size_t ob = (((size_t)bh * NH_ + hr) * T_ + tks[r]) * DH_ + d0;
    *(uint4*)&orowsb[ob]     = *(const uint4*)&ob16[0];
    *(uint4*)&orowsb[ob + 8] = *(const uint4*)&ob16[8];
  }
}

// ---------- combine hash rounds (bf16 in, bf16 out) ----------
__global__ __launch_bounds__(256) void combine_kernel(
    const unsigned short* __restrict__ orowsb, const float* __restrict__ logits,
    unsigned short* __restrict__ ocombb)
{
  const int gid = blockIdx.x * 4 + (threadIdx.x >> 6);
  const int lane = threadIdx.x & 63;
  const int bh = gid >> 12, t = gid & (T_ - 1);
  const int b = bh >> 3, hd = bh & 7;
  const size_t lb = (size_t)bh * NH_ * T_ + t;
  const float l0 = logits[lb];
  const float l1 = logits[lb + T_];
  const float l2 = logits[lb + 2 * T_];
  const float l3 = logits[lb + 3 * T_];
  const float m = fmaxf(fmaxf(l0, l1), fmaxf(l2, l3));
  const float w0 = __expf(l0 - m), w1 = __expf(l1 - m);
  const float w2 = __expf(l2 - m), w3 = __expf(l3 - m);
  const float inv = 1.f / (w0 + w1 + w2 + w3);
  const size_t rb = ((size_t)bh * NH_ * T_ + t) * DH_ + lane;
  const size_t step = (size_t)T_ * DH_;
  const float o = w0 * bf2f(orowsb[rb]) + w1 * bf2f(orowsb[rb + step])
                + w2 * bf2f(orowsb[rb + 2 * step]) + w3 * bf2f(orowsb[rb + 3 * step]);
  ocombb[((size_t)b * T_ + t) * D_ + hd * DH_ + lane] = f2bf(o * inv);
}

// ---------- LayerNorm ----------
__global__ __launch_bounds__(256) void ln_kernel(
    const float* __restrict__ y, const float* __restrict__ gamma,
    const float* __restrict__ beta, float* __restrict__ out)
{
  const int row = blockIdx.x * 4 + (threadIdx.x >> 6);
  const int lane = threadIdx.x & 63;
  const size_t base = (size_t)row * D_ + lane * 8;
  float x[8];
  *(float4*)&x[0] = *(const float4*)&y[base];
  *(float4*)&x[4] = *(const float4*)&y[base + 4];
  float s = 0.f;
#pragma unroll
  for (int i = 0; i < 8; ++i) s += x[i];
#pragma unroll
  for (int m = 32; m >= 1; m >>= 1) s += __shfl_xor(s, m);
  const float mu = s * (1.f / D_);
  float vs = 0.f;
#pragma unroll
  for (int i = 0; i < 8; ++i) { const float d = x[i] - mu; vs += d * d; }
#pragma unroll
  for (int m = 32; m >= 1; m >>= 1) vs += __shfl_xor(vs, m);
  const float rstd = rsqrtf(vs * (1.f / D_) + 1e-6f);
  float g[8], bt[8];
  *(float4*)&g[0]  = *(const float4*)&gamma[lane * 8];
  *(float4*)&g[4]  = *(const float4*)&gamma[lane * 8 + 4];
  *(float4*)&bt[0] = *(const float4*)&beta[lane * 8];
  *(float4*)&bt[4] = *(const float4*)&beta[lane * 8 + 4];
  float o[8];
#pragma unroll
  for (int i = 0; i < 8; ++i) o[i] = (x[i] - mu) * rstd * g[i] + bt[i];
  *(float4*)&out[base]     = make_float4(o[0], o[1], o[2], o[3]);
  *(float4*)&out[base + 4] = make_float4(o[4], o[5], o[6], o[7]);
}

extern "C" void kernel_launch(void* const* d_in, const int* in_sizes, int n_in,
                              void* d_out, int out_size, void* d_ws, size_t ws_size,
                              hipStream_t stream) {
  (void)in_sizes; (void)n_in; (void)out_size; (void)ws_size;
  const float* src   = (const float*)d_in[0];
  const float* Wqk   = (const float*)d_in[1];
  const float* Wv    = (const float*)d_in[2];
  const float* Wout  = (const float*)d_in[3];
  const float* bout  = (const float*)d_in[4];
  const float* W1    = (const float*)d_in[5];
  const float* b1    = (const float*)d_in[6];
  const float* W2    = (const float*)d_in[7];
  const float* b2    = (const float*)d_in[8];
  const float* gamma = (const float*)d_in[9];
  const float* beta  = (const float*)d_in[10];
  const float* rot   = (const float*)d_in[11];
  float* out = (float*)d_out;

  // ---- workspace layout (regions reused across pipeline phases) ----
  char* ws = (char*)d_ws;
  const size_t MB = 1024 * 1024;
  float*          qk      = (float*)(ws);                    // 32 MB; -> x_f32
  unsigned short* src_b   = (unsigned short*)(ws + 32 * MB); // 16 MB; -> ocomb_b
  unsigned short* v_b     = (unsigned short*)(ws + 48 * MB); // 16 MB; -> x_b
  unsigned short* orows_b = (unsigned short*)(ws + 64 * MB); // 64 MB; -> hidden_b
  float*          ybuf    = (float*)(ws + 128 * MB);         // 32 MB
  char* p = ws + 160 * MB;
  float* logits  = (float*)p; p += (size_t)BH_ * NH_ * T_ * 4;   // 2 MB
  int*   buckets = (int*)p;   p += (size_t)BH_ * NH_ * T_ * 4;   // 2 MB
  int*   sticker = (int*)p;   p += (size_t)BH_ * NTICK_ * 4;     // 2 MB
  int*   bstart  = (int*)p;   p += (size_t)BH_ * 256 * 4;
  float* invn    = (float*)p; p += (size_t)BH_ * T_ * 4;         // 0.5 MB
  unsigned short* WvT   = (unsigned short*)p; p += (size_t)D_ * D_ * 2;
  unsigned short* WoutT = (unsigned short*)p; p += (size_t)D_ * D_ * 2;
  unsigned short* W1T   = (unsigned short*)p; p += (size_t)FFN_ * D_ * 2;
  unsigned short* W2T   = (unsigned short*)p; p += (size_t)D_ * FFN_ * 2;

  float*          x_f32   = qk;       // after attn reads qk
  unsigned short* ocomb_b = src_b;    // after v GEMM reads src_b
  unsigned short* x_b     = v_b;      // after attn reads v_b
  unsigned short* hidden_b= orows_b;  // after combine reads orows_b

  // 0: conversions
  cvt_f2bf<<<M_ * D_ / 8 / 256, 256, 0, stream>>>(src, src_b, M_ * D_ / 8);
  transpose_f2bf<<<dim3(D_ / 32, D_ / 32), 256, 0, stream>>>(Wv, WvT, D_, D_);
  transpose_f2bf<<<dim3(D_ / 32, D_ / 32), 256, 0, stream>>>(Wout, WoutT, D_, D_);
  transpose_f2bf<<<dim3(FFN_ / 32, D_ / 32), 256, 0, stream>>>(W1, W1T, D_, FFN_);
  transpose_f2bf<<<dim3(D_ / 32, FFN_ / 32), 256, 0, stream>>>(W2, W2T, FFN_, D_);

  // 1: qk projection — fp32 (LSH argmax is precision-sensitive)
  gemm_f32<false, false, false><<<dim3(4, 128), 256, 0, stream>>>(
      src, Wqk, nullptr, nullptr, qk, M_, D_, D_);
  // 2: v projection — bf16 MFMA
  gemm_bf16<1, false, false, false><<<dim3(D_ / 128, M_ / 128), 256, 0, stream>>>(
      src_b, WvT, nullptr, nullptr, nullptr, v_b, M_, D_, D_);
  // 3: key inverse norms
  invnorm_kernel<<<BH_ * T_ / 4, 256, 0, stream>>>(qk, invn);
  // 4: LSH buckets
  hash_kernel<<<dim3(BH_, T_ / 64), 256, 0, stream>>>(qk, rot, buckets);
  // 5-6: counting sort
  hist_kernel<<<BH_, 256, 0, stream>>>(buckets, bstart);
  compact_kernel<<<dim3(256, BH_), 64, 0, stream>>>(buckets, bstart, sticker);
  // 7: chunked attention
  attn_kernel<<<dim3(CHUNKS_, BH_), 256, 0, stream>>>(
      qk, v_b, sticker, invn, orows_b, logits);
  // 8: combine hash rounds
  combine_kernel<<<BH_ * T_ / 4, 256, 0, stream>>>(orows_b, logits, ocomb_b);
  // 9: out projection + bias + residual(src): fp32 x + bf16 x
  gemm_bf16<2, true, false, true><<<dim3(D_ / 128, M_ / 128), 256, 0, stream>>>(
      ocomb_b, WoutT, bout, src, x_f32, x_b, M_, D_, D_);
  // 10: FFN1 (relu) -> bf16 hidden
  gemm_bf16<1, true, true, false><<<dim3(FFN_ / 128, M_ / 128), 256, 0, stream>>>(
      x_b, W1T, b1, nullptr, nullptr, hidden_b, M_, FFN_, D_);
  // 11: FFN2 + bias + residual(x) -> fp32 y
  gemm_bf16<0, true, false, true><<<dim3(D_ / 128, M_ / 128), 256, 0, stream>>>(
      hidden_b, W2T, b2, x_f32, ybuf, nullptr, M_, D_, FFN_);
  // 12: LayerNorm
  ln_kernel<<<M_ / 4, 256, 0, stream>>>(ybuf, gamma, beta, out);
}

// Round 3
// 716.116 us; speedup vs baseline: 2.5472x; 1.3582x over previous
//
#include <hip/hip_runtime.h>

#define B_ 4
#define T_ 4096
#define D_ 512
#define H_ 8
#define DH_ 64
#define NH_ 4
#define NB_ 64            // n_buckets = T/BUCKET
#define BH_ (B_*H_)       // 32
#define CHUNKS_ (NH_*NB_) // 256
#define NTICK_ (NH_*T_)   // 16384
#define M_ (B_*T_)        // 16384
#define FFN_ 2048

typedef __attribute__((ext_vector_type(8))) short bf16x8;
typedef __attribute__((ext_vector_type(4))) float f32x4;

// ---------- bf16 helpers (round-to-nearest-even) ----------
__device__ __forceinline__ unsigned short f2bf(float x) {
  unsigned int u = __float_as_uint(x);
  return (unsigned short)((u + 0x7FFFu + ((u >> 16) & 1u)) >> 16);
}
__device__ __forceinline__ float bf2f(unsigned short s) {
  return __uint_as_float(((unsigned int)s) << 16);
}

// ---------- async global->LDS, 16B per lane ----------
__device__ __forceinline__ void gld_lds16(const void* g, void* l) {
  __builtin_amdgcn_global_load_lds(
      (const __attribute__((address_space(1))) unsigned int*)g,
      (__attribute__((address_space(3))) unsigned int*)l, 16, 0, 0);
}

// swizzled LDS offsets (shorts): XOR 16B-granule with row&7 (T2)
__device__ __forceinline__ int off64(int row, int k) {
  return row * 64 + (((k >> 3) ^ (row & 7)) << 3) + (k & 7);
}
__device__ __forceinline__ int off128(int row, int k) {
  return row * 128 + (((k >> 3) ^ (row & 7)) << 3) + (k & 7);
}

// ---------- fp32 GEMM for qk (BM=128, BN=64; also emits bf16 copy) ----------
__global__ __launch_bounds__(256) void gemm_f32_qk(
    const float* __restrict__ A, const float* __restrict__ Bm,
    float* __restrict__ C, unsigned short* __restrict__ Cb,
    int M, int N, int K)
{
  __shared__ __align__(16) float As[16][132];   // transposed: As[k][m], 128 rows
  __shared__ __align__(16) float Bs[16][68];    // 64 cols
  const int tid = threadIdx.x;
  const int tx = tid & 15, ty = tid >> 4;       // 16 x 16 thread grid
  const int m0 = blockIdx.y * 128, n0 = blockIdx.x * 64;
  float acc[8][4];
#pragma unroll
  for (int i = 0; i < 8; ++i)
#pragma unroll
    for (int j = 0; j < 4; ++j) acc[i][j] = 0.f;

  for (int k0 = 0; k0 < K; k0 += 16) {
#pragma unroll
    for (int l = 0; l < 2; ++l) {
      const int idx = tid + l * 256;      // 0..511
      const int row = idx >> 2;           // 0..127
      const int kq = (idx & 3) << 2;      // 0,4,8,12
      const float4 a = *(const float4*)&A[(size_t)(m0 + row) * K + k0 + kq];
      As[kq + 0][row] = a.x; As[kq + 1][row] = a.y;
      As[kq + 2][row] = a.z; As[kq + 3][row] = a.w;
    }
    {
      const int kr = tid >> 4;            // 0..15
      const int c4 = (tid & 15) << 2;     // 0..60
      *(float4*)&Bs[kr][c4] = *(const float4*)&Bm[(size_t)(k0 + kr) * N + n0 + c4];
    }
    __syncthreads();
#pragma unroll
    for (int kk = 0; kk < 16; ++kk) {
      float a[8], b[4];
      *(float4*)&a[0] = *(const float4*)&As[kk][ty * 8];
      *(float4*)&a[4] = *(const float4*)&As[kk][ty * 8 + 4];
      *(float4*)&b[0] = *(const float4*)&Bs[kk][tx * 4];
#pragma unroll
      for (int i = 0; i < 8; ++i)
#pragma unroll
        for (int j = 0; j < 4; ++j)
          acc[i][j] = fmaf(a[i], b[j], acc[i][j]);
    }
    __syncthreads();
  }
#pragma unroll
  for (int i = 0; i < 8; ++i) {
    const size_t cb = (size_t)(m0 + ty * 8 + i) * N + n0 + tx * 4;
    *(float4*)&C[cb] = make_float4(acc[i][0], acc[i][1], acc[i][2], acc[i][3]);
    unsigned short o4[4] = {f2bf(acc[i][0]), f2bf(acc[i][1]),
                            f2bf(acc[i][2]), f2bf(acc[i][3])};
    *(uint2*)&Cb[cb] = *(const uint2*)&o4[0];
  }
}

// ---------- bf16 MFMA GEMM (m97 structure): C = op(A @ BT^T) ----------
// OUT_MODE: 0 = fp32 out, 1 = bf16 out, 2 = both.
template<int OUT_MODE, bool HAS_BIAS, bool RELU, bool HAS_RESID>
__global__ __launch_bounds__(256) void gemm_bf16(
    const unsigned short* __restrict__ A, const unsigned short* __restrict__ BT,
    const float* __restrict__ bias, const float* __restrict__ resid,
    float* __restrict__ Cf, unsigned short* __restrict__ Cb,
    int M, int N, int K)
{
  __shared__ __align__(16) unsigned short As[128 * 64];   // [row][k] linear
  __shared__ __align__(16) unsigned short Bs[128 * 64];   // [col][k] linear
  const int tid = threadIdx.x;
  const int lane = tid & 63;
  const int w = tid >> 6;
  const int wm = (w >> 1) * 64, wn = (w & 1) * 64;
  const int m0 = blockIdx.y * 128, n0 = blockIdx.x * 128;

  f32x4 acc[4][4];
#pragma unroll
  for (int i = 0; i < 4; ++i)
#pragma unroll
    for (int j = 0; j < 4; ++j) acc[i][j] = (f32x4){0.f, 0.f, 0.f, 0.f};

  const int srow = tid >> 3;
  const int skc  = (tid & 7) * 8;

  for (int k0 = 0; k0 < K; k0 += 64) {
#pragma unroll
    for (int ci = 0; ci < 4; ++ci) {
      const int row = ci * 32 + srow;
      gld_lds16(&A [(size_t)(m0 + row) * K + k0 + skc], &As[ci * 2048 + tid * 8]);
      gld_lds16(&BT[(size_t)(n0 + row) * K + k0 + skc], &Bs[ci * 2048 + tid * 8]);
    }
    __syncthreads();
#pragma unroll
    for (int kk = 0; kk < 64; kk += 32) {
      bf16x8 af[4], bfr[4];
#pragma unroll
      for (int i = 0; i < 4; ++i)
        af[i] = *(const bf16x8*)&As[(wm + i * 16 + (lane & 15)) * 64 + kk + (lane >> 4) * 8];
#pragma unroll
      for (int j = 0; j < 4; ++j)
        bfr[j] = *(const bf16x8*)&Bs[(wn + j * 16 + (lane & 15)) * 64 + kk + (lane >> 4) * 8];
#pragma unroll
      for (int i = 0; i < 4; ++i)
#pragma unroll
        for (int j = 0; j < 4; ++j)
          acc[i][j] = __builtin_amdgcn_mfma_f32_16x16x32_bf16(af[i], bfr[j], acc[i][j], 0, 0, 0);
    }
    __syncthreads();
  }

#pragma unroll
  for (int i = 0; i < 4; ++i) {
#pragma unroll
    for (int j = 0; j < 4; ++j) {
      const int col = n0 + wn + j * 16 + (lane & 15);
#pragma unroll
      for (int r = 0; r < 4; ++r) {
        const int row = m0 + wm + i * 16 + (lane >> 4) * 4 + r;
        float val = acc[i][j][r];
        if constexpr (HAS_BIAS) val += bias[col];
        if constexpr (RELU) val = fmaxf(val, 0.f);
        if constexpr (HAS_RESID) val += resid[(size_t)row * N + col];
        if constexpr (OUT_MODE == 0 || OUT_MODE == 2) Cf[(size_t)row * N + col] = val;
        if constexpr (OUT_MODE == 1 || OUT_MODE == 2) Cb[(size_t)row * N + col] = f2bf(val);
      }
    }
  }
}

// ---------- fp32 -> bf16 elementwise ----------
__global__ __launch_bounds__(256) void cvt_f2bf(
    const float* __restrict__ in, unsigned short* __restrict__ out, int n8)
{
  const int i = blockIdx.x * 256 + threadIdx.x;
  if (i >= n8) return;
  const size_t b = (size_t)i * 8;
  const float4 v0 = *(const float4*)&in[b];
  const float4 v1 = *(const float4*)&in[b + 4];
  unsigned short o[8] = {f2bf(v0.x), f2bf(v0.y), f2bf(v0.z), f2bf(v0.w),
                         f2bf(v1.x), f2bf(v1.y), f2bf(v1.z), f2bf(v1.w)};
  *(uint4*)&out[b] = *(const uint4*)&o[0];
}

// ---------- transpose + convert: W (KxN f32) -> WT (NxK bf16) ----------
__global__ __launch_bounds__(256) void transpose_f2bf(
    const float* __restrict__ W, unsigned short* __restrict__ WT, int K, int N)
{
  __shared__ float tile[32][33];
  const int k0 = blockIdx.y * 32, n0 = blockIdx.x * 32;
  const int tx = threadIdx.x & 31, ty = threadIdx.x >> 5;
#pragma unroll
  for (int r = 0; r < 32; r += 8)
    tile[ty + r][tx] = W[(size_t)(k0 + ty + r) * N + n0 + tx];
  __syncthreads();
#pragma unroll
  for (int r = 0; r < 32; r += 8)
    WT[(size_t)(n0 + ty + r) * K + k0 + tx] = f2bf(tile[tx][ty + r]);
}

// ---------- per-(bh,t) inverse key norm ----------
__global__ __launch_bounds__(256) void invnorm_kernel(
    const float* __restrict__ qk, float* __restrict__ invn)
{
  const int gid = blockIdx.x * 4 + (threadIdx.x >> 6);
  const int lane = threadIdx.x & 63;
  const int bh = gid >> 12, t = gid & (T_ - 1);
  const int b = bh >> 3, hd = bh & 7;
  const float x = qk[((size_t)b * T_ + t) * D_ + hd * DH_ + lane];
  float s = x * x;
#pragma unroll
  for (int m = 32; m >= 1; m >>= 1) s += __shfl_xor(s, m);
  if (lane == 0) invn[gid] = 1.0f / (sqrtf(s) + 1e-6f);
}

// ---------- LSH hashing: argmax over [rv,-rv] ----------
__global__ __launch_bounds__(256) void hash_kernel(
    const float* __restrict__ qk, const float* __restrict__ rot,
    int* __restrict__ buckets)
{
  __shared__ float rs[64 * NH_ * 32];   // rot[f][h][i]
  for (int i = threadIdx.x; i < 64 * NH_ * 32; i += 256) rs[i] = rot[i];
  __syncthreads();
  const int bh = blockIdx.x;
  const int b = bh >> 3, hd = bh & 7;
  const int wave = threadIdx.x >> 6, lane = threadIdx.x & 63;
  const int t0 = blockIdx.y * 64 + wave * 16;
  for (int tt = 0; tt < 16; ++tt) {
    const int t = t0 + tt;
    const float q = qk[((size_t)b * T_ + t) * D_ + hd * DH_ + lane];
#pragma unroll
    for (int pass = 0; pass < 2; ++pass) {
      const int h = pass * 2 + (lane >> 5);
      const int i = lane & 31;
      float acc = 0.f;
#pragma unroll
      for (int f = 0; f < 64; ++f)
        acc = fmaf(__shfl(q, f), rs[f * (NH_ * 32) + h * 32 + i], acc);
      float v = acc; int idx = i;
      if (-acc > acc) { v = -acc; idx = 32 + i; }
#pragma unroll
      for (int m = 16; m >= 1; m >>= 1) {
        const float ov = __shfl_xor(v, m);
        const int oi = __shfl_xor(idx, m);
        if (ov > v || (ov == v && oi < idx)) { v = ov; idx = oi; }
      }
      if ((lane & 31) == 0)
        buckets[((size_t)bh * NH_ + h) * T_ + t] = idx + h * NB_;
    }
  }
}

// ---------- per-bh bucket histogram + exclusive scan ----------
__global__ __launch_bounds__(256) void hist_kernel(
    const int* __restrict__ buckets, int* __restrict__ bstart)
{
  __shared__ int bins[256];
  const int bh = blockIdx.x;
  bins[threadIdx.x] = 0;
  __syncthreads();
  for (int e = threadIdx.x; e < NTICK_; e += 256)
    atomicAdd(&bins[buckets[(size_t)bh * NTICK_ + e]], 1);
  __syncthreads();
  if (threadIdx.x == 0) {
    int run = 0;
    for (int i = 0; i < 256; ++i) { const int c = bins[i]; bins[i] = run; run += c; }
  }
  __syncthreads();
  bstart[bh * 256 + threadIdx.x] = bins[threadIdx.x];
}

// ---------- stable compaction ----------
__global__ __launch_bounds__(64) void compact_kernel(
    const int* __restrict__ buckets, const int* __restrict__ bstart,
    int* __restrict__ sticker)
{
  const int bucket = blockIdx.x, bh = blockIdx.y;
  const int h = bucket >> 6;
  const int lane = threadIdx.x;
  int base = bstart[bh * 256 + bucket];
  const int* bk = buckets + (size_t)bh * NTICK_ + (size_t)h * T_;
  for (int it = 0; it < 64; ++it) {
    const int t = it * 64 + lane;
    const bool m = (bk[t] == bucket);
    const unsigned long long bal = __ballot(m);
    if (m) {
      const int pos = base + __popcll(bal & ((1ull << lane) - 1ull));
      sticker[(size_t)bh * NTICK_ + pos] = h * T_ + t;
    }
    base += __popcll(bal);
  }
}

// ---------- chunked LSH attention — MFMA version ----------
// Per block: chunk c of bh. Q=64 rows, K/V=128 rows (cur + prev chunk).
// dots: Q(64x64) @ K^T -> S(64x128); softmax in C/D regs; PV: P @ V -> O(64x64).
__global__ __launch_bounds__(256) void attn_kernel(
    const unsigned short* __restrict__ qkb, const unsigned short* __restrict__ vb,
    const int* __restrict__ sticker, const float* __restrict__ invn,
    unsigned short* __restrict__ orowsb, float* __restrict__ logits)
{
  __shared__ __align__(16) unsigned short Rs[128 * 64]; // qk rows; later O
  __shared__ __align__(16) unsigned short Vs[128 * 64]; // v rows; later P
  __shared__ __align__(16) unsigned short Vt[64 * 128]; // V^T [d][tok]
  __shared__ int tks[128];
  __shared__ float invs[128];

  const int c = blockIdx.x, bh = blockIdx.y;
  const int b = bh >> 3, hd = bh & 7;
  const int tid = threadIdx.x;
  const int hr = c >> 6;
  const int w = tid >> 6, lane = tid & 63, g = lane >> 4, cl = lane & 15;

  if (tid < 128) {
    const int sc = (tid < 64) ? c : ((c + CHUNKS_ - 1) & (CHUNKS_ - 1));
    const int tick = sticker[(size_t)bh * NTICK_ + sc * 64 + (tid & 63)];
    const int t = tick & (T_ - 1);
    tks[tid] = t;
    invs[tid] = invn[bh * T_ + t];
  }
  __syncthreads();

  // stage qk + v rows (bf16), swizzled
#pragma unroll
  for (int l = 0; l < 4; ++l) {
    const int idx = tid + l * 256;
    const int row = idx >> 3, k0 = (idx & 7) * 8;
    const size_t gb = ((size_t)b * T_ + tks[row]) * D_ + hd * DH_ + k0;
    *(uint4*)&Rs[off64(row, k0)] = *(const uint4*)&qkb[gb];
    *(uint4*)&Vs[off64(row, k0)] = *(const uint4*)&vb[gb];
  }
  __syncthreads();

  // transpose Vs -> Vt (reads Vs, writes Vt; independent of dots below)
#pragma unroll
  for (int l = 0; l < 4; ++l) {
    const int idx = tid + l * 256;
    const int d = idx & 63, tg = idx >> 6;     // tg: 16B token-granule 0..15
    unsigned short tmp[8];
#pragma unroll
    for (int e = 0; e < 8; ++e) tmp[e] = Vs[off64(tg * 8 + e, d)];
    *(uint4*)&Vt[off128(d, tg * 8)] = *(const uint4*)&tmp[0];
  }

  // dots: wave w -> query rows w*16..+15, all 128 keys
  f32x4 sacc[8];
#pragma unroll
  for (int j = 0; j < 8; ++j) sacc[j] = (f32x4){0.f, 0.f, 0.f, 0.f};
#pragma unroll
  for (int kk = 0; kk < 2; ++kk) {
    const bf16x8 aq = *(const bf16x8*)&Rs[off64(w * 16 + cl, kk * 32 + g * 8)];
#pragma unroll
    for (int j = 0; j < 8; ++j) {
      const bf16x8 bk = *(const bf16x8*)&Rs[off64(j * 16 + cl, kk * 32 + g * 8)];
      sacc[j] = __builtin_amdgcn_mfma_f32_16x16x32_bf16(aq, bk, sacc[j], 0, 0, 0);
    }
  }
  __syncthreads();   // Vt ready; all Rs/Vs reads done

  // scale + mask + softmax in C/D regs: row = w*16+g*4+r, col(key) = 16j+cl
  float iv[8]; int tk[8];
#pragma unroll
  for (int j = 0; j < 8; ++j) {
    iv[j] = invs[j * 16 + cl] * 0.125f;
    tk[j] = tks[j * 16 + cl];
  }
  int tq[4];
#pragma unroll
  for (int r = 0; r < 4; ++r) tq[r] = tks[w * 16 + g * 4 + r];

#pragma unroll
  for (int r = 0; r < 4; ++r) {
    float s[8];
    float mx = -3.0e38f;
#pragma unroll
    for (int j = 0; j < 8; ++j) {
      float d = sacc[j][r] * iv[j];
      if (tq[r] == tk[j]) d = -5.0e4f;
      s[j] = d;
      mx = fmaxf(mx, d);
    }
    mx = fmaxf(mx, __shfl_xor(mx, 1)); mx = fmaxf(mx, __shfl_xor(mx, 2));
    mx = fmaxf(mx, __shfl_xor(mx, 4)); mx = fmaxf(mx, __shfl_xor(mx, 8));
    float sum = 0.f;
#pragma unroll
    for (int j = 0; j < 8; ++j) { s[j] = __expf(s[j] - mx); sum += s[j]; }
    sum += __shfl_xor(sum, 1); sum += __shfl_xor(sum, 2);
    sum += __shfl_xor(sum, 4); sum += __shfl_xor(sum, 8);
    const float inv = 1.f / sum;
    const int row = w * 16 + g * 4 + r;
#pragma unroll
    for (int j = 0; j < 8; ++j)
      Vs[off128(row, j * 16 + cl)] = f2bf(s[j] * inv);   // P into Vs region
    if (cl == 0)
      logits[((size_t)bh * NH_ + hr) * T_ + tq[r]] = mx + __logf(sum);
  }
  __syncthreads();   // P visible

  // PV: wave w -> O rows w*16..+15 x 64 dims
  f32x4 oacc[4];
#pragma unroll
  for (int jd = 0; jd < 4; ++jd) oacc[jd] = (f32x4){0.f, 0.f, 0.f, 0.f};
#pragma unroll
  for (int ks = 0; ks < 4; ++ks) {
    const bf16x8 pa = *(const bf16x8*)&Vs[off128(w * 16 + cl, ks * 32 + g * 8)];
#pragma unroll
    for (int jd = 0; jd < 4; ++jd) {
      const bf16x8 vv = *(const bf16x8*)&Vt[off128(jd * 16 + cl, ks * 32 + g * 8)];
      oacc[jd] = __builtin_amdgcn_mfma_f32_16x16x32_bf16(pa, vv, oacc[jd], 0, 0, 0);
    }
  }
  // O (bf16) into Rs region
#pragma unroll
  for (int jd = 0; jd < 4; ++jd)
#pragma unroll
    for (int r = 0; r < 4; ++r)
      Rs[off64(w * 16 + g * 4 + r, jd * 16 + cl)] = f2bf(oacc[jd][r]);
  __syncthreads();

  // O rows -> global (coalesced 16B per lane, scattered 128B rows)
#pragma unroll
  for (int l = 0; l < 2; ++l) {
    const int idx = tid + l * 256;
    const int row = idx >> 3, k0 = (idx & 7) * 8;
    *(uint4*)&orowsb[(((size_t)bh * NH_ + hr) * T_ + tks[row]) * DH_ + k0] =
        *(const uint4*)&Rs[off64(row, k0)];
  }
}

// ---------- combine hash rounds (bf16 in, bf16 out) ----------
__global__ __launch_bounds__(256) void combine_kernel(
    const unsigned short* __restrict__ orowsb, const float* __restrict__ logits,
    unsigned short* __restrict__ ocombb)
{
  const int gid = blockIdx.x * 4 + (threadIdx.x >> 6);
  const int lane = threadIdx.x & 63;
  const int bh = gid >> 12, t = gid & (T_ - 1);
  const int b = bh >> 3, hd = bh & 7;
  const size_t lb = (size_t)bh * NH_ * T_ + t;
  const float l0 = logits[lb];
  const float l1 = logits[lb + T_];
  const float l2 = logits[lb + 2 * T_];
  const float l3 = logits[lb + 3 * T_];
  const float m = fmaxf(fmaxf(l0, l1), fmaxf(l2, l3));
  const float w0 = __expf(l0 - m), w1 = __expf(l1 - m);
  const float w2 = __expf(l2 - m), w3 = __expf(l3 - m);
  const float inv = 1.f / (w0 + w1 + w2 + w3);
  const size_t rb = ((size_t)bh * NH_ * T_ + t) * DH_ + lane;
  const size_t step = (size_t)T_ * DH_;
  const float o = w0 * bf2f(orowsb[rb]) + w1 * bf2f(orowsb[rb + step])
                + w2 * bf2f(orowsb[rb + 2 * step]) + w3 * bf2f(orowsb[rb + 3 * step]);
  ocombb[((size_t)b * T_ + t) * D_ + hd * DH_ + lane] = f2bf(o * inv);
}

// ---------- LayerNorm ----------
__global__ __launch_bounds__(256) void ln_kernel(
    const float* __restrict__ y, const float* __restrict__ gamma,
    const float* __restrict__ beta, float* __restrict__ out)
{
  const int row = blockIdx.x * 4 + (threadIdx.x >> 6);
  const int lane = threadIdx.x & 63;
  const size_t base = (size_t)row * D_ + lane * 8;
  float x[8];
  *(float4*)&x[0] = *(const float4*)&y[base];
  *(float4*)&x[4] = *(const float4*)&y[base + 4];
  float s = 0.f;
#pragma unroll
  for (int i = 0; i < 8; ++i) s += x[i];
#pragma unroll
  for (int m = 32; m >= 1; m >>= 1) s += __shfl_xor(s, m);
  const float mu = s * (1.f / D_);
  float vs = 0.f;
#pragma unroll
  for (int i = 0; i < 8; ++i) { const float d = x[i] - mu; vs += d * d; }
#pragma unroll
  for (int m = 32; m >= 1; m >>= 1) vs += __shfl_xor(vs, m);
  const float rstd = rsqrtf(vs * (1.f / D_) + 1e-6f);
  float g[8], bt[8];
  *(float4*)&g[0]  = *(const float4*)&gamma[lane * 8];
  *(float4*)&g[4]  = *(const float4*)&gamma[lane * 8 + 4];
  *(float4*)&bt[0] = *(const float4*)&beta[lane * 8];
  *(float4*)&bt[4] = *(const float4*)&beta[lane * 8 + 4];
  float o[8];
#pragma unroll
  for (int i = 0; i < 8; ++i) o[i] = (x[i] - mu) * rstd * g[i] + bt[i];
  *(float4*)&out[base]     = make_float4(o[0], o[1], o[2], o[3]);
  *(float4*)&out[base + 4] = make_float4(o[4], o[5], o[6], o[7]);
}

extern "C" void kernel_launch(void* const* d_in, const int* in_sizes, int n_in,
                              void* d_out, int out_size, void* d_ws, size_t ws_size,
                              hipStream_t stream) {
  (void)in_sizes; (void)n_in; (void)out_size; (void)ws_size;
  const float* src   = (const float*)d_in[0];
  const float* Wqk   = (const float*)d_in[1];
  const float* Wv    = (const float*)d_in[2];
  const float* Wout  = (const float*)d_in[3];
  const float* bout  = (const float*)d_in[4];
  const float* W1    = (const float*)d_in[5];
  const float* b1    = (const float*)d_in[6];
  const float* W2    = (const float*)d_in[7];
  const float* b2    = (const float*)d_in[8];
  const float* gamma = (const float*)d_in[9];
  const float* beta  = (const float*)d_in[10];
  const float* rot   = (const float*)d_in[11];
  float* out = (float*)d_out;

  // ---- workspace layout ----
  char* ws = (char*)d_ws;
  const size_t MB = 1024 * 1024;
  float*          qk      = (float*)(ws);                    // 32 MB; -> x_f32
  unsigned short* src_b   = (unsigned short*)(ws + 32 * MB); // 16 MB; -> ocomb_b
  unsigned short* v_b     = (unsigned short*)(ws + 48 * MB); // 16 MB; -> x_b
  unsigned short* orows_b = (unsigned short*)(ws + 64 * MB); // 64 MB; -> hidden_b
  float*          ybuf    = (float*)(ws + 128 * MB);         // 32 MB
  unsigned short* qk_b    = (unsigned short*)(ws + 160 * MB);// 16 MB
  char* p = ws + 176 * MB;
  float* logits  = (float*)p; p += (size_t)BH_ * NH_ * T_ * 4;
  int*   buckets = (int*)p;   p += (size_t)BH_ * NH_ * T_ * 4;
  int*   sticker = (int*)p;   p += (size_t)BH_ * NTICK_ * 4;
  int*   bstart  = (int*)p;   p += (size_t)BH_ * 256 * 4;
  float* invn    = (float*)p; p += (size_t)BH_ * T_ * 4;
  unsigned short* WvT   = (unsigned short*)p; p += (size_t)D_ * D_ * 2;
  unsigned short* WoutT = (unsigned short*)p; p += (size_t)D_ * D_ * 2;
  unsigned short* W1T   = (unsigned short*)p; p += (size_t)FFN_ * D_ * 2;
  unsigned short* W2T   = (unsigned short*)p; p += (size_t)D_ * FFN_ * 2;

  float*          x_f32    = qk;
  unsigned short* ocomb_b  = src_b;
  unsigned short* x_b      = v_b;
  unsigned short* hidden_b = orows_b;

  // 0: conversions
  cvt_f2bf<<<M_ * D_ / 8 / 256, 256, 0, stream>>>(src, src_b, M_ * D_ / 8);
  transpose_f2bf<<<dim3(D_ / 32, D_ / 32), 256, 0, stream>>>(Wv, WvT, D_, D_);
  transpose_f2bf<<<dim3(D_ / 32, D_ / 32), 256, 0, stream>>>(Wout, WoutT, D_, D_);
  transpose_f2bf<<<dim3(FFN_ / 32, D_ / 32), 256, 0, stream>>>(W1, W1T, D_, FFN_);
  transpose_f2bf<<<dim3(D_ / 32, FFN_ / 32), 256, 0, stream>>>(W2, W2T, FFN_, D_);

  // 1: qk projection — fp32 (LSH argmax precision-sensitive) + bf16 copy
  gemm_f32_qk<<<dim3(D_ / 64, M_ / 128), 256, 0, stream>>>(
      src, Wqk, qk, qk_b, M_, D_, D_);
  // 2: v projection — bf16 MFMA
  gemm_bf16<1, false, false, false><<<dim3(D_ / 128, M_ / 128), 256, 0, stream>>>(
      src_b, WvT, nullptr, nullptr, nullptr, v_b, M_, D_, D_);
  // 3: key inverse norms
  invnorm_kernel<<<BH_ * T_ / 4, 256, 0, stream>>>(qk, invn);
  // 4: LSH buckets
  hash_kernel<<<dim3(BH_, T_ / 64), 256, 0, stream>>>(qk, rot, buckets);
  // 5-6: counting sort
  hist_kernel<<<BH_, 256, 0, stream>>>(buckets, bstart);
  compact_kernel<<<dim3(256, BH_), 64, 0, stream>>>(buckets, bstart, sticker);
  // 7: chunked attention (MFMA)
  attn_kernel<<<dim3(CHUNKS_, BH_), 256, 0, stream>>>(
      qk_b, v_b, sticker, invn, orows_b, logits);
  // 8: combine hash rounds
  combine_kernel<<<BH_ * T_ / 4, 256, 0, stream>>>(orows_b, logits, ocomb_b);
  // 9: out projection + bias + residual(src)
  gemm_bf16<2, true, false, true><<<dim3(D_ / 128, M_ / 128), 256, 0, stream>>>(
      ocomb_b, WoutT, bout, src, x_f32, x_b, M_, D_, D_);
  // 10: FFN1 (relu)
  gemm_bf16<1, true, true, false><<<dim3(FFN_ / 128, M_ / 128), 256, 0, stream>>>(
      x_b, W1T, b1, nullptr, nullptr, hidden_b, M_, FFN_, D_);
  // 11: FFN2 + bias + residual(x)
  gemm_bf16<0, true, false, true><<<dim3(D_ / 128, M_ / 128), 256, 0, stream>>>(
      hidden_b, W2T, b2, x_f32, ybuf, nullptr, M_, D_, FFN_);
  // 12: LayerNorm
  ln_kernel<<<M_ / 4, 256, 0, stream>>>(ybuf, gamma, beta, out);
}

// Round 4
// 411.264 us; speedup vs baseline: 4.4354x; 1.7413x over previous
//
#include <hip/hip_runtime.h>

#define B_ 4
#define T_ 4096
#define D_ 512
#define H_ 8
#define DH_ 64
#define NH_ 4
#define NB_ 64            // n_buckets = T/BUCKET
#define BH_ (B_*H_)       // 32
#define CHUNKS_ (NH_*NB_) // 256
#define NTICK_ (NH_*T_)   // 16384
#define M_ (B_*T_)        // 16384
#define FFN_ 2048

typedef __attribute__((ext_vector_type(8))) short bf16x8;
typedef __attribute__((ext_vector_type(4))) float f32x4;

// ---------- bf16 helpers (round-to-nearest-even) ----------
__device__ __forceinline__ unsigned short f2bf(float x) {
  unsigned int u = __float_as_uint(x);
  return (unsigned short)((u + 0x7FFFu + ((u >> 16) & 1u)) >> 16);
}
__device__ __forceinline__ float bf2f(unsigned short s) {
  return __uint_as_float(((unsigned int)s) << 16);
}

// ---------- async global->LDS, 16B per lane ----------
__device__ __forceinline__ void gld_lds16(const void* g, void* l) {
  __builtin_amdgcn_global_load_lds(
      (const __attribute__((address_space(1))) unsigned int*)g,
      (__attribute__((address_space(3))) unsigned int*)l, 16, 0, 0);
}

// swizzled LDS offsets (shorts): XOR 16B-granule with row&7 (T2)
__device__ __forceinline__ int off64(int row, int k) {
  return row * 64 + (((k >> 3) ^ (row & 7)) << 3) + (k & 7);
}
__device__ __forceinline__ int off128(int row, int k) {
  return row * 128 + (((k >> 3) ^ (row & 7)) << 3) + (k & 7);
}

// ---------- bf16 MFMA GEMM (m97 structure): C = op(A @ BT^T) ----------
// A: MxK bf16, row stride lda. BT: NxK bf16, row stride ldbt.
// OUT_MODE: 0 = fp32 out, 1 = bf16 out, 2 = both.
template<int OUT_MODE, bool HAS_BIAS, bool RELU, bool HAS_RESID>
__global__ __launch_bounds__(256) void gemm_bf16(
    const unsigned short* __restrict__ A, const unsigned short* __restrict__ BT,
    const float* __restrict__ bias, const float* __restrict__ resid,
    float* __restrict__ Cf, unsigned short* __restrict__ Cb,
    int M, int N, int K, int lda, int ldbt)
{
  __shared__ __align__(16) unsigned short As[128 * 64];   // [row][k] linear
  __shared__ __align__(16) unsigned short Bs[128 * 64];   // [col][k] linear
  const int tid = threadIdx.x;
  const int lane = tid & 63;
  const int w = tid >> 6;
  const int wm = (w >> 1) * 64, wn = (w & 1) * 64;
  const int m0 = blockIdx.y * 128, n0 = blockIdx.x * 128;

  f32x4 acc[4][4];
#pragma unroll
  for (int i = 0; i < 4; ++i)
#pragma unroll
    for (int j = 0; j < 4; ++j) acc[i][j] = (f32x4){0.f, 0.f, 0.f, 0.f};

  const int srow = tid >> 3;
  const int skc  = (tid & 7) * 8;

  for (int k0 = 0; k0 < K; k0 += 64) {
#pragma unroll
    for (int ci = 0; ci < 4; ++ci) {
      const int row = ci * 32 + srow;
      gld_lds16(&A [(size_t)(m0 + row) * lda  + k0 + skc], &As[ci * 2048 + tid * 8]);
      gld_lds16(&BT[(size_t)(n0 + row) * ldbt + k0 + skc], &Bs[ci * 2048 + tid * 8]);
    }
    __syncthreads();
#pragma unroll
    for (int kk = 0; kk < 64; kk += 32) {
      bf16x8 af[4], bfr[4];
#pragma unroll
      for (int i = 0; i < 4; ++i)
        af[i] = *(const bf16x8*)&As[(wm + i * 16 + (lane & 15)) * 64 + kk + (lane >> 4) * 8];
#pragma unroll
      for (int j = 0; j < 4; ++j)
        bfr[j] = *(const bf16x8*)&Bs[(wn + j * 16 + (lane & 15)) * 64 + kk + (lane >> 4) * 8];
#pragma unroll
      for (int i = 0; i < 4; ++i)
#pragma unroll
        for (int j = 0; j < 4; ++j)
          acc[i][j] = __builtin_amdgcn_mfma_f32_16x16x32_bf16(af[i], bfr[j], acc[i][j], 0, 0, 0);
    }
    __syncthreads();
  }

#pragma unroll
  for (int i = 0; i < 4; ++i) {
#pragma unroll
    for (int j = 0; j < 4; ++j) {
      const int col = n0 + wn + j * 16 + (lane & 15);
#pragma unroll
      for (int r = 0; r < 4; ++r) {
        const int row = m0 + wm + i * 16 + (lane >> 4) * 4 + r;
        float val = acc[i][j][r];
        if constexpr (HAS_BIAS) val += bias[col];
        if constexpr (RELU) val = fmaxf(val, 0.f);
        if constexpr (HAS_RESID) val += resid[(size_t)row * N + col];
        if constexpr (OUT_MODE == 0 || OUT_MODE == 2) Cf[(size_t)row * N + col] = val;
        if constexpr (OUT_MODE == 1 || OUT_MODE == 2) Cb[(size_t)row * N + col] = f2bf(val);
      }
    }
  }
}

// ---------- split fp32 row(Dd) -> bf16 pair row(2*Dd): [hi | lo] ----------
__global__ __launch_bounds__(256) void split_pair_kernel(
    const float* __restrict__ in, unsigned short* __restrict__ outp, int n8, int Dd)
{
  const int i = blockIdx.x * 256 + threadIdx.x;
  if (i >= n8) return;
  const int gpr = Dd >> 3;
  const int m = i / gpr, d0 = (i - m * gpr) * 8;
  float x[8];
  *(float4*)&x[0] = *(const float4*)&in[(size_t)m * Dd + d0];
  *(float4*)&x[4] = *(const float4*)&in[(size_t)m * Dd + d0 + 4];
  unsigned short hi[8], lo[8];
#pragma unroll
  for (int e = 0; e < 8; ++e) {
    hi[e] = f2bf(x[e]);
    lo[e] = f2bf(x[e] - bf2f(hi[e]));
  }
  *(uint4*)&outp[(size_t)m * 2 * Dd + d0]      = *(const uint4*)&hi[0];
  *(uint4*)&outp[(size_t)m * 2 * Dd + Dd + d0] = *(const uint4*)&lo[0];
}

// ---------- transpose + convert: W (KxN f32) -> WT (NxK bf16) ----------
__global__ __launch_bounds__(256) void transpose_f2bf(
    const float* __restrict__ W, unsigned short* __restrict__ WT, int K, int N)
{
  __shared__ float tile[32][33];
  const int k0 = blockIdx.y * 32, n0 = blockIdx.x * 32;
  const int tx = threadIdx.x & 31, ty = threadIdx.x >> 5;
#pragma unroll
  for (int r = 0; r < 32; r += 8)
    tile[ty + r][tx] = W[(size_t)(k0 + ty + r) * N + n0 + tx];
  __syncthreads();
#pragma unroll
  for (int r = 0; r < 32; r += 8)
    WT[(size_t)(n0 + ty + r) * K + k0 + tx] = f2bf(tile[tx][ty + r]);
}

// ---------- transpose + split: W (KxN f32) -> WT (Nx2K bf16: [hi|lo]) ----------
__global__ __launch_bounds__(256) void transpose_split_f2bf(
    const float* __restrict__ W, unsigned short* __restrict__ WT, int K, int N)
{
  __shared__ float tile[32][33];
  const int k0 = blockIdx.y * 32, n0 = blockIdx.x * 32;
  const int tx = threadIdx.x & 31, ty = threadIdx.x >> 5;
#pragma unroll
  for (int r = 0; r < 32; r += 8)
    tile[ty + r][tx] = W[(size_t)(k0 + ty + r) * N + n0 + tx];
  __syncthreads();
#pragma unroll
  for (int r = 0; r < 32; r += 8) {
    const float x = tile[tx][ty + r];
    const unsigned short hi = f2bf(x);
    WT[(size_t)(n0 + ty + r) * 2 * K + k0 + tx]     = hi;
    WT[(size_t)(n0 + ty + r) * 2 * K + K + k0 + tx] = f2bf(x - bf2f(hi));
  }
}

// ---------- per-(bh,t) inverse key norm ----------
__global__ __launch_bounds__(256) void invnorm_kernel(
    const float* __restrict__ qk, float* __restrict__ invn)
{
  const int gid = blockIdx.x * 4 + (threadIdx.x >> 6);
  const int lane = threadIdx.x & 63;
  const int bh = gid >> 12, t = gid & (T_ - 1);
  const int b = bh >> 3, hd = bh & 7;
  const float x = qk[((size_t)b * T_ + t) * D_ + hd * DH_ + lane];
  float s = x * x;
#pragma unroll
  for (int m = 32; m >= 1; m >>= 1) s += __shfl_xor(s, m);
  if (lane == 0) invn[gid] = 1.0f / (sqrtf(s) + 1e-6f);
}

// ---------- LSH hashing as GEMM + fused argmax ----------
// Per block: 128 tokens x 128 cols (h*32+i), K=64. rv = qk_head @ rot.
// buckets[bh][h][t] = argmax_{idx in 0..63} [rv, -rv] + h*NB_.
__global__ __launch_bounds__(256) void hash_gemm_kernel(
    const float* __restrict__ qk, const float* __restrict__ rot,
    int* __restrict__ buckets)
{
  __shared__ __align__(16) float As[64][136];   // [k][m]
  __shared__ __align__(16) float Bs[64][132];   // [k][n]
  const int tid = threadIdx.x;
  const int tx = tid & 15, ty = tid >> 4;
  const int t0 = blockIdx.x * 128, bh = blockIdx.y;
  const int b = bh >> 3, hd = bh & 7;

  // stage A (128 token head-rows, transposed) — one-shot, conflicts OK
#pragma unroll
  for (int l = 0; l < 8; ++l) {
    const int idx = tid + l * 256;     // 0..2047
    const int row = idx >> 4;          // 0..127
    const int kq = (idx & 15) << 2;    // 0..60
    const float4 a = *(const float4*)&qk[((size_t)b * T_ + t0 + row) * D_ + hd * DH_ + kq];
    As[kq + 0][row] = a.x; As[kq + 1][row] = a.y;
    As[kq + 2][row] = a.z; As[kq + 3][row] = a.w;
  }
  // stage B: rot is (64 x 128) row-major already
#pragma unroll
  for (int l = 0; l < 8; ++l) {
    const int idx = tid + l * 256;     // 0..2047
    const int kr = idx >> 5;           // 0..63
    const int c4 = (idx & 31) << 2;    // 0..124
    *(float4*)&Bs[kr][c4] = *(const float4*)&rot[kr * 128 + c4];
  }
  __syncthreads();

  float acc[8][8];
#pragma unroll
  for (int i = 0; i < 8; ++i)
#pragma unroll
    for (int j = 0; j < 8; ++j) acc[i][j] = 0.f;

#pragma unroll 4
  for (int kk = 0; kk < 64; ++kk) {
    float a[8], bq[8];
    *(float4*)&a[0]  = *(const float4*)&As[kk][ty * 8];
    *(float4*)&a[4]  = *(const float4*)&As[kk][ty * 8 + 4];
    *(float4*)&bq[0] = *(const float4*)&Bs[kk][tx * 8];
    *(float4*)&bq[4] = *(const float4*)&Bs[kk][tx * 8 + 4];
#pragma unroll
    for (int i = 0; i < 8; ++i)
#pragma unroll
      for (int j = 0; j < 8; ++j)
        acc[i][j] = fmaf(a[i], bq[j], acc[i][j]);
  }
  __syncthreads();   // done with As/Bs; reuse as argmax scratch

  float* pval = &As[0][0];        // [token][16]
  int*   pidx = (int*)&Bs[0][0];  // [token][16]

  const int i0 = (tx & 3) * 8;    // local i base within hash h = tx>>2
#pragma unroll
  for (int r = 0; r < 8; ++r) {
    float v = -3.0e38f; int idx = 127;
#pragma unroll
    for (int j = 0; j < 8; ++j) {
      const float p = acc[r][j];
      const int li = i0 + j;
      if (p > v || (p == v && li < idx)) { v = p; idx = li; }
      const float n = -p;
      const int ni = 32 + li;
      if (n > v || (n == v && ni < idx)) { v = n; idx = ni; }
    }
    pval[(ty * 8 + r) * 16 + tx] = v;
    pidx[(ty * 8 + r) * 16 + tx] = idx;
  }
  __syncthreads();

#pragma unroll
  for (int l = 0; l < 2; ++l) {
    const int id = tid + l * 256;       // 0..511 = 128 tokens x 4 h
    const int tok = id >> 2, hh = id & 3;
    float v = pval[tok * 16 + hh * 4];
    int idx = pidx[tok * 16 + hh * 4];
#pragma unroll
    for (int e = 1; e < 4; ++e) {
      const float ov = pval[tok * 16 + hh * 4 + e];
      const int oi = pidx[tok * 16 + hh * 4 + e];
      if (ov > v || (ov == v && oi < idx)) { v = ov; idx = oi; }
    }
    buckets[((size_t)bh * NH_ + hh) * T_ + t0 + tok] = idx + hh * NB_;
  }
}

// ---------- per-bh bucket histogram + exclusive scan ----------
__global__ __launch_bounds__(256) void hist_kernel(
    const int* __restrict__ buckets, int* __restrict__ bstart)
{
  __shared__ int bins[256];
  const int bh = blockIdx.x;
  bins[threadIdx.x] = 0;
  __syncthreads();
  for (int e = threadIdx.x; e < NTICK_; e += 256)
    atomicAdd(&bins[buckets[(size_t)bh * NTICK_ + e]], 1);
  __syncthreads();
  if (threadIdx.x == 0) {
    int run = 0;
    for (int i = 0; i < 256; ++i) { const int c = bins[i]; bins[i] = run; run += c; }
  }
  __syncthreads();
  bstart[bh * 256 + threadIdx.x] = bins[threadIdx.x];
}

// ---------- stable compaction ----------
__global__ __launch_bounds__(64) void compact_kernel(
    const int* __restrict__ buckets, const int* __restrict__ bstart,
    int* __restrict__ sticker)
{
  const int bucket = blockIdx.x, bh = blockIdx.y;
  const int h = bucket >> 6;
  const int lane = threadIdx.x;
  int base = bstart[bh * 256 + bucket];
  const int* bk = buckets + (size_t)bh * NTICK_ + (size_t)h * T_;
  for (int it = 0; it < 64; ++it) {
    const int t = it * 64 + lane;
    const bool m = (bk[t] == bucket);
    const unsigned long long bal = __ballot(m);
    if (m) {
      const int pos = base + __popcll(bal & ((1ull << lane) - 1ull));
      sticker[(size_t)bh * NTICK_ + pos] = h * T_ + t;
    }
    base += __popcll(bal);
  }
}

// ---------- chunked LSH attention — MFMA version ----------
__global__ __launch_bounds__(256) void attn_kernel(
    const unsigned short* __restrict__ qkb, const unsigned short* __restrict__ vb,
    const int* __restrict__ sticker, const float* __restrict__ invn,
    unsigned short* __restrict__ orowsb, float* __restrict__ logits)
{
  __shared__ __align__(16) unsigned short Rs[128 * 64]; // qk rows; later O
  __shared__ __align__(16) unsigned short Vs[128 * 64]; // v rows; later P
  __shared__ __align__(16) unsigned short Vt[64 * 128]; // V^T [d][tok]
  __shared__ int tks[128];
  __shared__ float invs[128];

  const int c = blockIdx.x, bh = blockIdx.y;
  const int b = bh >> 3, hd = bh & 7;
  const int tid = threadIdx.x;
  const int hr = c >> 6;
  const int w = tid >> 6, lane = tid & 63, g = lane >> 4, cl = lane & 15;

  if (tid < 128) {
    const int sc = (tid < 64) ? c : ((c + CHUNKS_ - 1) & (CHUNKS_ - 1));
    const int tick = sticker[(size_t)bh * NTICK_ + sc * 64 + (tid & 63)];
    const int t = tick & (T_ - 1);
    tks[tid] = t;
    invs[tid] = invn[bh * T_ + t];
  }
  __syncthreads();

#pragma unroll
  for (int l = 0; l < 4; ++l) {
    const int idx = tid + l * 256;
    const int row = idx >> 3, k0 = (idx & 7) * 8;
    const size_t gb = ((size_t)b * T_ + tks[row]) * D_ + hd * DH_ + k0;
    *(uint4*)&Rs[off64(row, k0)] = *(const uint4*)&qkb[gb];
    *(uint4*)&Vs[off64(row, k0)] = *(const uint4*)&vb[gb];
  }
  __syncthreads();

  // transpose Vs -> Vt
#pragma unroll
  for (int l = 0; l < 4; ++l) {
    const int idx = tid + l * 256;
    const int d = idx & 63, tg = idx >> 6;
    unsigned short tmp[8];
#pragma unroll
    for (int e = 0; e < 8; ++e) tmp[e] = Vs[off64(tg * 8 + e, d)];
    *(uint4*)&Vt[off128(d, tg * 8)] = *(const uint4*)&tmp[0];
  }

  // dots: wave w -> query rows w*16..+15, all 128 keys
  f32x4 sacc[8];
#pragma unroll
  for (int j = 0; j < 8; ++j) sacc[j] = (f32x4){0.f, 0.f, 0.f, 0.f};
#pragma unroll
  for (int kk = 0; kk < 2; ++kk) {
    const bf16x8 aq = *(const bf16x8*)&Rs[off64(w * 16 + cl, kk * 32 + g * 8)];
#pragma unroll
    for (int j = 0; j < 8; ++j) {
      const bf16x8 bk = *(const bf16x8*)&Rs[off64(j * 16 + cl, kk * 32 + g * 8)];
      sacc[j] = __builtin_amdgcn_mfma_f32_16x16x32_bf16(aq, bk, sacc[j], 0, 0, 0);
    }
  }
  __syncthreads();

  float iv[8]; int tk[8];
#pragma unroll
  for (int j = 0; j < 8; ++j) {
    iv[j] = invs[j * 16 + cl] * 0.125f;
    tk[j] = tks[j * 16 + cl];
  }
  int tq[4];
#pragma unroll
  for (int r = 0; r < 4; ++r) tq[r] = tks[w * 16 + g * 4 + r];

#pragma unroll
  for (int r = 0; r < 4; ++r) {
    float s[8];
    float mx = -3.0e38f;
#pragma unroll
    for (int j = 0; j < 8; ++j) {
      float d = sacc[j][r] * iv[j];
      if (tq[r] == tk[j]) d = -5.0e4f;
      s[j] = d;
      mx = fmaxf(mx, d);
    }
    mx = fmaxf(mx, __shfl_xor(mx, 1)); mx = fmaxf(mx, __shfl_xor(mx, 2));
    mx = fmaxf(mx, __shfl_xor(mx, 4)); mx = fmaxf(mx, __shfl_xor(mx, 8));
    float sum = 0.f;
#pragma unroll
    for (int j = 0; j < 8; ++j) { s[j] = __expf(s[j] - mx); sum += s[j]; }
    sum += __shfl_xor(sum, 1); sum += __shfl_xor(sum, 2);
    sum += __shfl_xor(sum, 4); sum += __shfl_xor(sum, 8);
    const float inv = 1.f / sum;
    const int row = w * 16 + g * 4 + r;
#pragma unroll
    for (int j = 0; j < 8; ++j)
      Vs[off128(row, j * 16 + cl)] = f2bf(s[j] * inv);
    if (cl == 0)
      logits[((size_t)bh * NH_ + hr) * T_ + tq[r]] = mx + __logf(sum);
  }
  __syncthreads();

  // PV
  f32x4 oacc[4];
#pragma unroll
  for (int jd = 0; jd < 4; ++jd) oacc[jd] = (f32x4){0.f, 0.f, 0.f, 0.f};
#pragma unroll
  for (int ks = 0; ks < 4; ++ks) {
    const bf16x8 pa = *(const bf16x8*)&Vs[off128(w * 16 + cl, ks * 32 + g * 8)];
#pragma unroll
    for (int jd = 0; jd < 4; ++jd) {
      const bf16x8 vv = *(const bf16x8*)&Vt[off128(jd * 16 + cl, ks * 32 + g * 8)];
      oacc[jd] = __builtin_amdgcn_mfma_f32_16x16x32_bf16(pa, vv, oacc[jd], 0, 0, 0);
    }
  }
#pragma unroll
  for (int jd = 0; jd < 4; ++jd)
#pragma unroll
    for (int r = 0; r < 4; ++r)
      Rs[off64(w * 16 + g * 4 + r, jd * 16 + cl)] = f2bf(oacc[jd][r]);
  __syncthreads();

#pragma unroll
  for (int l = 0; l < 2; ++l) {
    const int idx = tid + l * 256;
    const int row = idx >> 3, k0 = (idx & 7) * 8;
    *(uint4*)&orowsb[(((size_t)bh * NH_ + hr) * T_ + tks[row]) * DH_ + k0] =
        *(const uint4*)&Rs[off64(row, k0)];
  }
}

// ---------- combine hash rounds ----------
__global__ __launch_bounds__(256) void combine_kernel(
    const unsigned short* __restrict__ orowsb, const float* __restrict__ logits,
    unsigned short* __restrict__ ocombb)
{
  const int gid = blockIdx.x * 4 + (threadIdx.x >> 6);
  const int lane = threadIdx.x & 63;
  const int bh = gid >> 12, t = gid & (T_ - 1);
  const int b = bh >> 3, hd = bh & 7;
  const size_t lb = (size_t)bh * NH_ * T_ + t;
  const float l0 = logits[lb];
  const float l1 = logits[lb + T_];
  const float l2 = logits[lb + 2 * T_];
  const float l3 = logits[lb + 3 * T_];
  const float m = fmaxf(fmaxf(l0, l1), fmaxf(l2, l3));
  const float w0 = __expf(l0 - m), w1 = __expf(l1 - m);
  const float w2 = __expf(l2 - m), w3 = __expf(l3 - m);
  const float inv = 1.f / (w0 + w1 + w2 + w3);
  const size_t rb = ((size_t)bh * NH_ * T_ + t) * DH_ + lane;
  const size_t step = (size_t)T_ * DH_;
  const float o = w0 * bf2f(orowsb[rb]) + w1 * bf2f(orowsb[rb + step])
                + w2 * bf2f(orowsb[rb + 2 * step]) + w3 * bf2f(orowsb[rb + 3 * step]);
  ocombb[((size_t)b * T_ + t) * D_ + hd * DH_ + lane] = f2bf(o * inv);
}

// ---------- LayerNorm ----------
__global__ __launch_bounds__(256) void ln_kernel(
    const float* __restrict__ y, const float* __restrict__ gamma,
    const float* __restrict__ beta, float* __restrict__ out)
{
  const int row = blockIdx.x * 4 + (threadIdx.x >> 6);
  const int lane = threadIdx.x & 63;
  const size_t base = (size_t)row * D_ + lane * 8;
  float x[8];
  *(float4*)&x[0] = *(const float4*)&y[base];
  *(float4*)&x[4] = *(const float4*)&y[base + 4];
  float s = 0.f;
#pragma unroll
  for (int i = 0; i < 8; ++i) s += x[i];
#pragma unroll
  for (int m = 32; m >= 1; m >>= 1) s += __shfl_xor(s, m);
  const float mu = s * (1.f / D_);
  float vs = 0.f;
#pragma unroll
  for (int i = 0; i < 8; ++i) { const float d = x[i] - mu; vs += d * d; }
#pragma unroll
  for (int m = 32; m >= 1; m >>= 1) vs += __shfl_xor(vs, m);
  const float rstd = rsqrtf(vs * (1.f / D_) + 1e-6f);
  float g[8], bt[8];
  *(float4*)&g[0]  = *(const float4*)&gamma[lane * 8];
  *(float4*)&g[4]  = *(const float4*)&gamma[lane * 8 + 4];
  *(float4*)&bt[0] = *(const float4*)&beta[lane * 8];
  *(float4*)&bt[4] = *(const float4*)&beta[lane * 8 + 4];
  float o[8];
#pragma unroll
  for (int i = 0; i < 8; ++i) o[i] = (x[i] - mu) * rstd * g[i] + bt[i];
  *(float4*)&out[base]     = make_float4(o[0], o[1], o[2], o[3]);
  *(float4*)&out[base + 4] = make_float4(o[4], o[5], o[6], o[7]);
}

extern "C" void kernel_launch(void* const* d_in, const int* in_sizes, int n_in,
                              void* d_out, int out_size, void* d_ws, size_t ws_size,
                              hipStream_t stream) {
  (void)in_sizes; (void)n_in; (void)out_size; (void)ws_size;
  const float* src   = (const float*)d_in[0];
  const float* Wqk   = (const float*)d_in[1];
  const float* Wv    = (const float*)d_in[2];
  const float* Wout  = (const float*)d_in[3];
  const float* bout  = (const float*)d_in[4];
  const float* W1    = (const float*)d_in[5];
  const float* b1    = (const float*)d_in[6];
  const float* W2    = (const float*)d_in[7];
  const float* b2    = (const float*)d_in[8];
  const float* gamma = (const float*)d_in[9];
  const float* beta  = (const float*)d_in[10];
  const float* rot   = (const float*)d_in[11];
  float* out = (float*)d_out;

  // ---- workspace layout ----
  char* ws = (char*)d_ws;
  const size_t MB = 1024 * 1024;
  float*          qk       = (float*)(ws);                     // 32 MB; -> x_f32
  unsigned short* src_pair = (unsigned short*)(ws + 32 * MB);  // 32 MB [hi|lo]; -> ocomb_b/ybuf
  unsigned short* v_b      = (unsigned short*)(ws + 64 * MB);  // 16 MB; -> x_b
  unsigned short* orows_b  = (unsigned short*)(ws + 80 * MB);  // 64 MB; -> hidden_b
  unsigned short* qk_b     = (unsigned short*)(ws + 144 * MB); // 16 MB
  char* p = ws + 160 * MB;
  float* logits  = (float*)p; p += (size_t)BH_ * NH_ * T_ * 4;
  int*   buckets = (int*)p;   p += (size_t)BH_ * NH_ * T_ * 4;
  int*   sticker = (int*)p;   p += (size_t)BH_ * NTICK_ * 4;
  int*   bstart  = (int*)p;   p += (size_t)BH_ * 256 * 4;
  float* invn    = (float*)p; p += (size_t)BH_ * T_ * 4;
  unsigned short* WvT    = (unsigned short*)p; p += (size_t)D_ * D_ * 2;
  unsigned short* WoutT  = (unsigned short*)p; p += (size_t)D_ * D_ * 2;
  unsigned short* W1T    = (unsigned short*)p; p += (size_t)FFN_ * D_ * 2;
  unsigned short* W2T    = (unsigned short*)p; p += (size_t)D_ * FFN_ * 2;
  unsigned short* WqkTp  = (unsigned short*)p; p += (size_t)D_ * 2 * D_ * 2;

  float*          x_f32    = qk;                          // after attn
  unsigned short* ocomb_b  = src_pair;                    // after qk/v GEMMs
  float*          ybuf     = (float*)(ws + 32 * MB);      // after ocomb_b dead
  unsigned short* x_b      = v_b;                         // after attn
  unsigned short* hidden_b = orows_b;                     // after combine

  // 0: conversions
  split_pair_kernel<<<M_ * D_ / 8 / 256, 256, 0, stream>>>(src, src_pair, M_ * D_ / 8, D_);
  transpose_split_f2bf<<<dim3(D_ / 32, D_ / 32), 256, 0, stream>>>(Wqk, WqkTp, D_, D_);
  transpose_f2bf<<<dim3(D_ / 32, D_ / 32), 256, 0, stream>>>(Wv, WvT, D_, D_);
  transpose_f2bf<<<dim3(D_ / 32, D_ / 32), 256, 0, stream>>>(Wout, WoutT, D_, D_);
  transpose_f2bf<<<dim3(FFN_ / 32, D_ / 32), 256, 0, stream>>>(W1, W1T, D_, FFN_);
  transpose_f2bf<<<dim3(D_ / 32, FFN_ / 32), 256, 0, stream>>>(W2, W2T, FFN_, D_);

  // 1: qk projection — split-bf16 MFMA (K=1024 = [hi|lo]), fp32+bf16 out
  gemm_bf16<2, false, false, false><<<dim3(D_ / 128, M_ / 128), 256, 0, stream>>>(
      src_pair, WqkTp, nullptr, nullptr, qk, qk_b, M_, D_, 2 * D_, 2 * D_, 2 * D_);
  // 2: v projection — bf16 MFMA (hi half of src_pair = bf16(src))
  gemm_bf16<1, false, false, false><<<dim3(D_ / 128, M_ / 128), 256, 0, stream>>>(
      src_pair, WvT, nullptr, nullptr, nullptr, v_b, M_, D_, D_, 2 * D_, D_);
  // 3: key inverse norms
  invnorm_kernel<<<BH_ * T_ / 4, 256, 0, stream>>>(qk, invn);
  // 4: LSH buckets (GEMM + fused argmax)
  hash_gemm_kernel<<<dim3(T_ / 128, BH_), 256, 0, stream>>>(qk, rot, buckets);
  // 5-6: counting sort
  hist_kernel<<<BH_, 256, 0, stream>>>(buckets, bstart);
  compact_kernel<<<dim3(256, BH_), 64, 0, stream>>>(buckets, bstart, sticker);
  // 7: chunked attention (MFMA)
  attn_kernel<<<dim3(CHUNKS_, BH_), 256, 0, stream>>>(
      qk_b, v_b, sticker, invn, orows_b, logits);
  // 8: combine hash rounds
  combine_kernel<<<BH_ * T_ / 4, 256, 0, stream>>>(orows_b, logits, ocomb_b);
  // 9: out projection + bias + residual(src)
  gemm_bf16<2, true, false, true><<<dim3(D_ / 128, M_ / 128), 256, 0, stream>>>(
      ocomb_b, WoutT, bout, src, x_f32, x_b, M_, D_, D_, D_, D_);
  // 10: FFN1 (relu)
  gemm_bf16<1, true, true, false><<<dim3(FFN_ / 128, M_ / 128), 256, 0, stream>>>(
      x_b, W1T, b1, nullptr, nullptr, hidden_b, M_, FFN_, D_, D_, D_);
  // 11: FFN2 + bias + residual(x)
  gemm_bf16<0, true, false, true><<<dim3(D_ / 128, M_ / 128), 256, 0, stream>>>(
      hidden_b, W2T, b2, x_f32, ybuf, nullptr, M_, D_, FFN_, FFN_, FFN_);
  // 12: LayerNorm
  ln_kernel<<<M_ / 4, 256, 0, stream>>>(ybuf, gamma, beta, out);
}

// Round 5
// 387.993 us; speedup vs baseline: 4.7014x; 1.0600x over previous
//
#include <hip/hip_runtime.h>

#define B_ 4
#define T_ 4096
#define D_ 512
#define H_ 8
#define DH_ 64
#define NH_ 4
#define NB_ 64            // n_buckets = T/BUCKET
#define BH_ (B_*H_)       // 32
#define CHUNKS_ (NH_*NB_) // 256
#define NTICK_ (NH_*T_)   // 16384
#define M_ (B_*T_)        // 16384
#define FFN_ 2048

typedef __attribute__((ext_vector_type(8))) short bf16x8;
typedef __attribute__((ext_vector_type(4))) float f32x4;

// ---------- bf16 helpers (round-to-nearest-even) ----------
__device__ __forceinline__ unsigned short f2bf(float x) {
  unsigned int u = __float_as_uint(x);
  return (unsigned short)((u + 0x7FFFu + ((u >> 16) & 1u)) >> 16);
}
__device__ __forceinline__ float bf2f(unsigned short s) {
  return __uint_as_float(((unsigned int)s) << 16);
}

// ---------- async global->LDS, 16B per lane ----------
__device__ __forceinline__ void gld_lds16(const void* g, void* l) {
  __builtin_amdgcn_global_load_lds(
      (const __attribute__((address_space(1))) unsigned int*)g,
      (__attribute__((address_space(3))) unsigned int*)l, 16, 0, 0);
}

// swizzled LDS offsets (shorts): XOR 16B-granule with row&7 (T2)
__device__ __forceinline__ int off64(int row, int k) {
  return row * 64 + (((k >> 3) ^ (row & 7)) << 3) + (k & 7);
}
__device__ __forceinline__ int off128(int row, int k) {
  return row * 128 + (((k >> 3) ^ (row & 7)) << 3) + (k & 7);
}

// ---------- bf16 MFMA GEMM (m97 structure): C = op(A @ BT^T) ----------
// A: MxK bf16 (stride lda). BT: NxK bf16 (stride ldbt).
// OUT_MODE: 1 = bf16 out (coalesced restage), 2 = + f32 scalar out.
// HAS_RESID: bf16 residual added during coalesced copy-out (stride ldr).
// FUSE_INV: also emit invn[(b*8+head)*T + t] = 1/(||row_head||+1e-6)  (qk only)
template<int OUT_MODE, bool HAS_BIAS, bool RELU, bool HAS_RESID, bool FUSE_INV>
__global__ __launch_bounds__(256) void gemm_bf16(
    const unsigned short* __restrict__ A, const unsigned short* __restrict__ BT,
    const float* __restrict__ bias, const unsigned short* __restrict__ resid,
    float* __restrict__ Cf, unsigned short* __restrict__ Cb,
    float* __restrict__ invn,
    int M, int N, int K, int lda, int ldbt, int ldr)
{
  __shared__ __align__(16) unsigned short smem[2 * 128 * 64];  // As | Bs, then C-tile
  unsigned short* As = smem;
  unsigned short* Bs = smem + 128 * 64;
  const int tid = threadIdx.x;
  const int lane = tid & 63;
  const int w = tid >> 6;
  const int wm = (w >> 1) * 64, wn = (w & 1) * 64;
  const int g = lane >> 4, cl = lane & 15;
  const int m0 = blockIdx.y * 128, n0 = blockIdx.x * 128;

  f32x4 acc[4][4];
#pragma unroll
  for (int i = 0; i < 4; ++i)
#pragma unroll
    for (int j = 0; j < 4; ++j) acc[i][j] = (f32x4){0.f, 0.f, 0.f, 0.f};

  const int srow = tid >> 3;
  const int skc  = (tid & 7) * 8;

  for (int k0 = 0; k0 < K; k0 += 64) {
#pragma unroll
    for (int ci = 0; ci < 4; ++ci) {
      const int row = ci * 32 + srow;
      gld_lds16(&A [(size_t)(m0 + row) * lda  + k0 + skc], &As[ci * 2048 + tid * 8]);
      gld_lds16(&BT[(size_t)(n0 + row) * ldbt + k0 + skc], &Bs[ci * 2048 + tid * 8]);
    }
    __syncthreads();
#pragma unroll
    for (int kk = 0; kk < 64; kk += 32) {
      bf16x8 af[4], bfr[4];
#pragma unroll
      for (int i = 0; i < 4; ++i)
        af[i] = *(const bf16x8*)&As[(wm + i * 16 + cl) * 64 + kk + g * 8];
#pragma unroll
      for (int j = 0; j < 4; ++j)
        bfr[j] = *(const bf16x8*)&Bs[(wn + j * 16 + cl) * 64 + kk + g * 8];
#pragma unroll
      for (int i = 0; i < 4; ++i)
#pragma unroll
        for (int j = 0; j < 4; ++j)
          acc[i][j] = __builtin_amdgcn_mfma_f32_16x16x32_bf16(af[i], bfr[j], acc[i][j], 0, 0, 0);
    }
    __syncthreads();
  }

  // ---- epilogue: bias/relu in regs -> LDS C-tile (swizzled) -> coalesced out
  float bv[4];
  if constexpr (HAS_BIAS) {
#pragma unroll
    for (int j = 0; j < 4; ++j) bv[j] = bias[n0 + wn + j * 16 + cl];
  }
#pragma unroll
  for (int i = 0; i < 4; ++i) {
#pragma unroll
    for (int r = 0; r < 4; ++r) {
      const int lrow = wm + i * 16 + g * 4 + r;
      float ss = 0.f;
#pragma unroll
      for (int j = 0; j < 4; ++j) {
        const int lcol = wn + j * 16 + cl;
        float val = acc[i][j][r];
        if constexpr (HAS_BIAS) val += bv[j];
        if constexpr (RELU) val = fmaxf(val, 0.f);
        if constexpr (FUSE_INV) ss += val * val;
        if constexpr (OUT_MODE == 2) Cf[(size_t)(m0 + lrow) * N + n0 + lcol] = val;
        smem[lrow * 128 + (lcol ^ ((lrow & 7) << 3))] = f2bf(val);
      }
      if constexpr (FUSE_INV) {
        ss += __shfl_xor(ss, 1); ss += __shfl_xor(ss, 2);
        ss += __shfl_xor(ss, 4); ss += __shfl_xor(ss, 8);
        if (cl == 0) {
          const int m = m0 + lrow;
          const int bb = m >> 12, t = m & (T_ - 1);
          const int hh = ((n0 + wn) >> 6) & 7;
          invn[((size_t)(bb * 8 + hh)) * T_ + t] = 1.0f / (sqrtf(ss) + 1e-6f);
        }
      }
    }
  }
  __syncthreads();
#pragma unroll
  for (int l = 0; l < 8; ++l) {
    const int idx = tid + l * 256;
    const int row = idx >> 4, c8 = (idx & 15) * 8;
    uint4 u = *(const uint4*)&smem[row * 128 + (c8 ^ ((row & 7) << 3))];
    if constexpr (HAS_RESID) {
      const uint4 rv = *(const uint4*)&resid[(size_t)(m0 + row) * ldr + n0 + c8];
      unsigned short* sp = (unsigned short*)&u;
      const unsigned short* rp = (const unsigned short*)&rv;
#pragma unroll
      for (int e = 0; e < 8; ++e) sp[e] = f2bf(bf2f(sp[e]) + bf2f(rp[e]));
    }
    *(uint4*)&Cb[(size_t)(m0 + row) * N + n0 + c8] = u;
  }
}

// ---------- split fp32 row(Dd) -> bf16 pair row(2*Dd): [hi | lo] ----------
__global__ __launch_bounds__(256) void split_pair_kernel(
    const float* __restrict__ in, unsigned short* __restrict__ outp, int n8, int Dd)
{
  const int i = blockIdx.x * 256 + threadIdx.x;
  if (i >= n8) return;
  const int gpr = Dd >> 3;
  const int m = i / gpr, d0 = (i - m * gpr) * 8;
  float x[8];
  *(float4*)&x[0] = *(const float4*)&in[(size_t)m * Dd + d0];
  *(float4*)&x[4] = *(const float4*)&in[(size_t)m * Dd + d0 + 4];
  unsigned short hi[8], lo[8];
#pragma unroll
  for (int e = 0; e < 8; ++e) {
    hi[e] = f2bf(x[e]);
    lo[e] = f2bf(x[e] - bf2f(hi[e]));
  }
  *(uint4*)&outp[(size_t)m * 2 * Dd + d0]      = *(const uint4*)&hi[0];
  *(uint4*)&outp[(size_t)m * 2 * Dd + Dd + d0] = *(const uint4*)&lo[0];
}

// ---------- fused weight prep: transpose(+split) all 5 weights ----------
__global__ __launch_bounds__(256) void prep_weights(
    const float* __restrict__ Wqk, const float* __restrict__ Wv,
    const float* __restrict__ Wout, const float* __restrict__ W1,
    const float* __restrict__ W2,
    unsigned short* __restrict__ WqkTp, unsigned short* __restrict__ WvT,
    unsigned short* __restrict__ WoutT, unsigned short* __restrict__ W1T,
    unsigned short* __restrict__ W2T)
{
  __shared__ float tile[32][33];
  int bid = blockIdx.x;
  const float* W; unsigned short* WT; int K, N, bx, by; bool split = false;
  if (bid < 256)        { W = Wqk;  WT = WqkTp; K = 512;  N = 512;  split = true;
                          bx = bid & 15; by = bid >> 4; }
  else if (bid < 512)   { bid -= 256;  W = Wv;   WT = WvT;   K = 512;  N = 512;
                          bx = bid & 15; by = bid >> 4; }
  else if (bid < 768)   { bid -= 512;  W = Wout; WT = WoutT; K = 512;  N = 512;
                          bx = bid & 15; by = bid >> 4; }
  else if (bid < 1792)  { bid -= 768;  W = W1;   WT = W1T;   K = 512;  N = 2048;
                          bx = bid & 63; by = bid >> 6; }
  else                  { bid -= 1792; W = W2;   WT = W2T;   K = 2048; N = 512;
                          bx = bid & 15; by = bid >> 4; }
  const int k0 = by * 32, n0 = bx * 32;
  const int tx = threadIdx.x & 31, ty = threadIdx.x >> 5;
#pragma unroll
  for (int r = 0; r < 32; r += 8)
    tile[ty + r][tx] = W[(size_t)(k0 + ty + r) * N + n0 + tx];
  __syncthreads();
  const int ld = split ? 2 * K : K;
#pragma unroll
  for (int r = 0; r < 32; r += 8) {
    const float x = tile[tx][ty + r];
    const unsigned short hi = f2bf(x);
    WT[(size_t)(n0 + ty + r) * ld + k0 + tx] = hi;
    if (split)
      WT[(size_t)(n0 + ty + r) * ld + K + k0 + tx] = f2bf(x - bf2f(hi));
  }
}

// ---------- LSH hashing as GEMM + fused argmax (reads fp32 qk) ----------
__global__ __launch_bounds__(256) void hash_gemm_kernel(
    const float* __restrict__ qk, const float* __restrict__ rot,
    int* __restrict__ buckets)
{
  __shared__ __align__(16) float As[64][136];   // [k][m]
  __shared__ __align__(16) float Bs[64][132];   // [k][n]
  const int tid = threadIdx.x;
  const int tx = tid & 15, ty = tid >> 4;
  const int t0 = blockIdx.x * 128, bh = blockIdx.y;
  const int b = bh >> 3, hd = bh & 7;

#pragma unroll
  for (int l = 0; l < 8; ++l) {
    const int idx = tid + l * 256;
    const int row = idx >> 4;
    const int kq = (idx & 15) << 2;
    const float4 a = *(const float4*)&qk[((size_t)b * T_ + t0 + row) * D_ + hd * DH_ + kq];
    As[kq + 0][row] = a.x; As[kq + 1][row] = a.y;
    As[kq + 2][row] = a.z; As[kq + 3][row] = a.w;
  }
#pragma unroll
  for (int l = 0; l < 8; ++l) {
    const int idx = tid + l * 256;
    const int kr = idx >> 5;
    const int c4 = (idx & 31) << 2;
    *(float4*)&Bs[kr][c4] = *(const float4*)&rot[kr * 128 + c4];
  }
  __syncthreads();

  float acc[8][8];
#pragma unroll
  for (int i = 0; i < 8; ++i)
#pragma unroll
    for (int j = 0; j < 8; ++j) acc[i][j] = 0.f;

#pragma unroll 4
  for (int kk = 0; kk < 64; ++kk) {
    float a[8], bq[8];
    *(float4*)&a[0]  = *(const float4*)&As[kk][ty * 8];
    *(float4*)&a[4]  = *(const float4*)&As[kk][ty * 8 + 4];
    *(float4*)&bq[0] = *(const float4*)&Bs[kk][tx * 8];
    *(float4*)&bq[4] = *(const float4*)&Bs[kk][tx * 8 + 4];
#pragma unroll
    for (int i = 0; i < 8; ++i)
#pragma unroll
      for (int j = 0; j < 8; ++j)
        acc[i][j] = fmaf(a[i], bq[j], acc[i][j]);
  }
  __syncthreads();

  float* pval = &As[0][0];
  int*   pidx = (int*)&Bs[0][0];
  const int i0 = (tx & 3) * 8;
#pragma unroll
  for (int r = 0; r < 8; ++r) {
    float v = -3.0e38f; int idx = 127;
#pragma unroll
    for (int j = 0; j < 8; ++j) {
      const float p = acc[r][j];
      const int li = i0 + j;
      if (p > v || (p == v && li < idx)) { v = p; idx = li; }
      const float n = -p;
      const int ni = 32 + li;
      if (n > v || (n == v && ni < idx)) { v = n; idx = ni; }
    }
    pval[(ty * 8 + r) * 16 + tx] = v;
    pidx[(ty * 8 + r) * 16 + tx] = idx;
  }
  __syncthreads();

#pragma unroll
  for (int l = 0; l < 2; ++l) {
    const int id = tid + l * 256;
    const int tok = id >> 2, hh = id & 3;
    float v = pval[tok * 16 + hh * 4];
    int idx = pidx[tok * 16 + hh * 4];
#pragma unroll
    for (int e = 1; e < 4; ++e) {
      const float ov = pval[tok * 16 + hh * 4 + e];
      const int oi = pidx[tok * 16 + hh * 4 + e];
      if (ov > v || (ov == v && oi < idx)) { v = ov; idx = oi; }
    }
    buckets[((size_t)bh * NH_ + hh) * T_ + t0 + tok] = idx + hh * NB_;
  }
}

// ---------- per-bh bucket histogram + exclusive scan ----------
__global__ __launch_bounds__(256) void hist_kernel(
    const int* __restrict__ buckets, int* __restrict__ bstart)
{
  __shared__ int bins[256];
  const int bh = blockIdx.x;
  bins[threadIdx.x] = 0;
  __syncthreads();
  for (int e = threadIdx.x; e < NTICK_; e += 256)
    atomicAdd(&bins[buckets[(size_t)bh * NTICK_ + e]], 1);
  __syncthreads();
  if (threadIdx.x == 0) {
    int run = 0;
    for (int i = 0; i < 256; ++i) { const int c = bins[i]; bins[i] = run; run += c; }
  }
  __syncthreads();
  bstart[bh * 256 + threadIdx.x] = bins[threadIdx.x];
}

// ---------- stable compaction ----------
__global__ __launch_bounds__(64) void compact_kernel(
    const int* __restrict__ buckets, const int* __restrict__ bstart,
    int* __restrict__ sticker)
{
  const int bucket = blockIdx.x, bh = blockIdx.y;
  const int h = bucket >> 6;
  const int lane = threadIdx.x;
  int base = bstart[bh * 256 + bucket];
  const int* bk = buckets + (size_t)bh * NTICK_ + (size_t)h * T_;
  for (int it = 0; it < 64; ++it) {
    const int t = it * 64 + lane;
    const bool m = (bk[t] == bucket);
    const unsigned long long bal = __ballot(m);
    if (m) {
      const int pos = base + __popcll(bal & ((1ull << lane) - 1ull));
      sticker[(size_t)bh * NTICK_ + pos] = h * T_ + t;
    }
    base += __popcll(bal);
  }
}

// ---------- chunked LSH attention — MFMA, 33 KB LDS ----------
// Rs: qk rows -> P (unnormalized) -> O.  Vs: v rows -> V^T.
__global__ __launch_bounds__(256) void attn_kernel(
    const unsigned short* __restrict__ qkb, const unsigned short* __restrict__ vb,
    const int* __restrict__ sticker, const float* __restrict__ invn,
    unsigned short* __restrict__ orowsb, float* __restrict__ logits)
{
  __shared__ __align__(16) unsigned short Rs[128 * 64];
  __shared__ __align__(16) unsigned short Vs[128 * 64];
  __shared__ int tks[128];
  __shared__ float invs[128];

  const int c = blockIdx.x, bh = blockIdx.y;
  const int b = bh >> 3, hd = bh & 7;
  const int tid = threadIdx.x;
  const int hr = c >> 6;
  const int w = tid >> 6, lane = tid & 63, g = lane >> 4, cl = lane & 15;

  if (tid < 128) {
    const int sc = (tid < 64) ? c : ((c + CHUNKS_ - 1) & (CHUNKS_ - 1));
    const int tick = sticker[(size_t)bh * NTICK_ + sc * 64 + (tid & 63)];
    const int t = tick & (T_ - 1);
    tks[tid] = t;
    invs[tid] = invn[bh * T_ + t];
  }
  __syncthreads();

  // stage qk + v rows (bf16), swizzled
#pragma unroll
  for (int l = 0; l < 4; ++l) {
    const int idx = tid + l * 256;
    const int row = idx >> 3, k0 = (idx & 7) * 8;
    const size_t gb = ((size_t)b * T_ + tks[row]) * D_ + hd * DH_ + k0;
    *(uint4*)&Rs[off64(row, k0)] = *(const uint4*)&qkb[gb];
    *(uint4*)&Vs[off64(row, k0)] = *(const uint4*)&vb[gb];
  }
  __syncthreads();

  // dots (MFMA from Rs) + transpose-read of Vs into regs
  f32x4 sacc[8];
#pragma unroll
  for (int j = 0; j < 8; ++j) sacc[j] = (f32x4){0.f, 0.f, 0.f, 0.f};
#pragma unroll
  for (int kk = 0; kk < 2; ++kk) {
    const bf16x8 aq = *(const bf16x8*)&Rs[off64(w * 16 + cl, kk * 32 + g * 8)];
#pragma unroll
    for (int j = 0; j < 8; ++j) {
      const bf16x8 bk = *(const bf16x8*)&Rs[off64(j * 16 + cl, kk * 32 + g * 8)];
      sacc[j] = __builtin_amdgcn_mfma_f32_16x16x32_bf16(aq, bk, sacc[j], 0, 0, 0);
    }
  }
  unsigned short tr[4][8];
#pragma unroll
  for (int q = 0; q < 4; ++q) {
    const int gi = tid + q * 256;
    const int d = gi & 63, tg = gi >> 6;
#pragma unroll
    for (int e = 0; e < 8; ++e) tr[q][e] = Vs[off64(tg * 8 + e, d)];
  }
  __syncthreads();

  // write V^T into Vs; softmax from sacc -> unnormalized P into Rs
#pragma unroll
  for (int q = 0; q < 4; ++q) {
    const int gi = tid + q * 256;
    const int d = gi & 63, tg = gi >> 6;
    *(uint4*)&Vs[off128(d, tg * 8)] = *(const uint4*)&tr[q][0];
  }

  float iv[8]; int tk[8];
#pragma unroll
  for (int j = 0; j < 8; ++j) {
    iv[j] = invs[j * 16 + cl] * 0.125f;
    tk[j] = tks[j * 16 + cl];
  }
  float pinv[4];
#pragma unroll
  for (int r = 0; r < 4; ++r) {
    const int row = w * 16 + g * 4 + r;
    const int tq = tks[row];
    float s[8];
    float mx = -3.0e38f;
#pragma unroll
    for (int j = 0; j < 8; ++j) {
      float d = sacc[j][r] * iv[j];
      if (tq == tk[j]) d = -5.0e4f;
      s[j] = d;
      mx = fmaxf(mx, d);
    }
    mx = fmaxf(mx, __shfl_xor(mx, 1)); mx = fmaxf(mx, __shfl_xor(mx, 2));
    mx = fmaxf(mx, __shfl_xor(mx, 4)); mx = fmaxf(mx, __shfl_xor(mx, 8));
    float sum = 0.f;
#pragma unroll
    for (int j = 0; j < 8; ++j) { s[j] = __expf(s[j] - mx); sum += s[j]; }
    sum += __shfl_xor(sum, 1); sum += __shfl_xor(sum, 2);
    sum += __shfl_xor(sum, 4); sum += __shfl_xor(sum, 8);
    pinv[r] = 1.f / sum;
#pragma unroll
    for (int j = 0; j < 8; ++j)
      Rs[off128(row, j * 16 + cl)] = f2bf(s[j]);       // unnormalized
    if (cl == 0)
      logits[((size_t)bh * NH_ + hr) * T_ + tq] = mx + __logf(sum);
  }
  __syncthreads();

  // PV: A = P (Rs), B = V^T (Vs)
  f32x4 oacc[4];
#pragma unroll
  for (int jd = 0; jd < 4; ++jd) oacc[jd] = (f32x4){0.f, 0.f, 0.f, 0.f};
#pragma unroll
  for (int ks = 0; ks < 4; ++ks) {
    const bf16x8 pa = *(const bf16x8*)&Rs[off128(w * 16 + cl, ks * 32 + g * 8)];
#pragma unroll
    for (int jd = 0; jd < 4; ++jd) {
      const bf16x8 vv = *(const bf16x8*)&Vs[off128(jd * 16 + cl, ks * 32 + g * 8)];
      oacc[jd] = __builtin_amdgcn_mfma_f32_16x16x32_bf16(pa, vv, oacc[jd], 0, 0, 0);
    }
  }
  __syncthreads();   // P fully consumed across waves before O overwrites Rs

  // O (scaled by 1/sum) into Rs, then coalesced scatter to global
#pragma unroll
  for (int jd = 0; jd < 4; ++jd)
#pragma unroll
    for (int r = 0; r < 4; ++r)
      Rs[off64(w * 16 + g * 4 + r, jd * 16 + cl)] = f2bf(oacc[jd][r] * pinv[r]);
  __syncthreads();

#pragma unroll
  for (int l = 0; l < 2; ++l) {
    const int idx = tid + l * 256;
    const int row = idx >> 3, k0 = (idx & 7) * 8;
    *(uint4*)&orowsb[(((size_t)bh * NH_ + hr) * T_ + tks[row]) * DH_ + k0] =
        *(const uint4*)&Rs[off64(row, k0)];
  }
}

// ---------- combine hash rounds ----------
__global__ __launch_bounds__(256) void combine_kernel(
    const unsigned short* __restrict__ orowsb, const float* __restrict__ logits,
    unsigned short* __restrict__ ocombb)
{
  const int gid = blockIdx.x * 4 + (threadIdx.x >> 6);
  const int lane = threadIdx.x & 63;
  const int bh = gid >> 12, t = gid & (T_ - 1);
  const int b = bh >> 3, hd = bh & 7;
  const size_t lb = (size_t)bh * NH_ * T_ + t;
  const float l0 = logits[lb];
  const float l1 = logits[lb + T_];
  const float l2 = logits[lb + 2 * T_];
  const float l3 = logits[lb + 3 * T_];
  const float m = fmaxf(fmaxf(l0, l1), fmaxf(l2, l3));
  const float w0 = __expf(l0 - m), w1 = __expf(l1 - m);
  const float w2 = __expf(l2 - m), w3 = __expf(l3 - m);
  const float inv = 1.f / (w0 + w1 + w2 + w3);
  const size_t rb = ((size_t)bh * NH_ * T_ + t) * DH_ + lane;
  const size_t step = (size_t)T_ * DH_;
  const float o = w0 * bf2f(orowsb[rb]) + w1 * bf2f(orowsb[rb + step])
                + w2 * bf2f(orowsb[rb + 2 * step]) + w3 * bf2f(orowsb[rb + 3 * step]);
  ocombb[((size_t)b * T_ + t) * D_ + hd * DH_ + lane] = f2bf(o * inv);
}

// ---------- LayerNorm (bf16 in, fp32 out) ----------
__global__ __launch_bounds__(256) void ln_kernel(
    const unsigned short* __restrict__ yb, const float* __restrict__ gamma,
    const float* __restrict__ beta, float* __restrict__ out)
{
  const int row = blockIdx.x * 4 + (threadIdx.x >> 6);
  const int lane = threadIdx.x & 63;
  const size_t base = (size_t)row * D_ + lane * 8;
  const uint4 u = *(const uint4*)&yb[base];
  const unsigned short* up = (const unsigned short*)&u;
  float x[8];
#pragma unroll
  for (int i = 0; i < 8; ++i) x[i] = bf2f(up[i]);
  float s = 0.f;
#pragma unroll
  for (int i = 0; i < 8; ++i) s += x[i];
#pragma unroll
  for (int m = 32; m >= 1; m >>= 1) s += __shfl_xor(s, m);
  const float mu = s * (1.f / D_);
  float vs = 0.f;
#pragma unroll
  for (int i = 0; i < 8; ++i) { const float d = x[i] - mu; vs += d * d; }
#pragma unroll
  for (int m = 32; m >= 1; m >>= 1) vs += __shfl_xor(vs, m);
  const float rstd = rsqrtf(vs * (1.f / D_) + 1e-6f);
  float gm[8], bt[8];
  *(float4*)&gm[0] = *(const float4*)&gamma[lane * 8];
  *(float4*)&gm[4] = *(const float4*)&gamma[lane * 8 + 4];
  *(float4*)&bt[0] = *(const float4*)&beta[lane * 8];
  *(float4*)&bt[4] = *(const float4*)&beta[lane * 8 + 4];
  float o[8];
#pragma unroll
  for (int i = 0; i < 8; ++i) o[i] = (x[i] - mu) * rstd * gm[i] + bt[i];
  *(float4*)&out[base]     = make_float4(o[0], o[1], o[2], o[3]);
  *(float4*)&out[base + 4] = make_float4(o[4], o[5], o[6], o[7]);
}

extern "C" void kernel_launch(void* const* d_in, const int* in_sizes, int n_in,
                              void* d_out, int out_size, void* d_ws, size_t ws_size,
                              hipStream_t stream) {
  (void)in_sizes; (void)n_in; (void)out_size; (void)ws_size;
  const float* src   = (const float*)d_in[0];
  const float* Wqk   = (const float*)d_in[1];
  const float* Wv    = (const float*)d_in[2];
  const float* Wout  = (const float*)d_in[3];
  const float* bout  = (const float*)d_in[4];
  const float* W1    = (const float*)d_in[5];
  const float* b1    = (const float*)d_in[6];
  const float* W2    = (const float*)d_in[7];
  const float* b2    = (const float*)d_in[8];
  const float* gamma = (const float*)d_in[9];
  const float* beta  = (const float*)d_in[10];
  const float* rot   = (const float*)d_in[11];
  float* out = (float*)d_out;

  // ---- workspace layout ----
  char* ws = (char*)d_ws;
  const size_t MB = 1024 * 1024;
  float*          qk       = (float*)(ws);                     // 32 MB; dead after hash
  unsigned short* src_pair = (unsigned short*)(ws + 32 * MB);  // 32 MB [hi|lo]; live thru Wout
  unsigned short* v_b      = (unsigned short*)(ws + 64 * MB);  // 16 MB; -> x_b after attn
  unsigned short* orows_b  = (unsigned short*)(ws + 80 * MB);  // 64 MB; -> hidden_b
  unsigned short* qk_b     = (unsigned short*)(ws + 144 * MB); // 16 MB; -> ocomb_b after attn
  char* p = ws + 160 * MB;
  float* logits  = (float*)p; p += (size_t)BH_ * NH_ * T_ * 4;
  int*   buckets = (int*)p;   p += (size_t)BH_ * NH_ * T_ * 4;
  int*   sticker = (int*)p;   p += (size_t)BH_ * NTICK_ * 4;
  int*   bstart  = (int*)p;   p += (size_t)BH_ * 256 * 4;
  float* invn    = (float*)p; p += (size_t)BH_ * T_ * 4;
  unsigned short* WvT    = (unsigned short*)p; p += (size_t)D_ * D_ * 2;
  unsigned short* WoutT  = (unsigned short*)p; p += (size_t)D_ * D_ * 2;
  unsigned short* W1T    = (unsigned short*)p; p += (size_t)FFN_ * D_ * 2;
  unsigned short* W2T    = (unsigned short*)p; p += (size_t)D_ * FFN_ * 2;
  unsigned short* WqkTp  = (unsigned short*)p; p += (size_t)D_ * 2 * D_ * 2;

  unsigned short* ocomb_b  = qk_b;                 // after attn consumed qk_b
  unsigned short* x_b      = v_b;                  // after attn consumed v_b
  unsigned short* hidden_b = orows_b;              // after combine consumed orows
  unsigned short* ybuf_b   = (unsigned short*)ws;  // after hash consumed qk f32

  // 0: conversions (2 launches)
  prep_weights<<<2816, 256, 0, stream>>>(Wqk, Wv, Wout, W1, W2,
                                         WqkTp, WvT, WoutT, W1T, W2T);
  split_pair_kernel<<<M_ * D_ / 8 / 256, 256, 0, stream>>>(src, src_pair, M_ * D_ / 8, D_);

  // 1: qk projection — split-bf16 MFMA (K=1024, bit-identical to r4) + fused invnorm
  gemm_bf16<2, false, false, false, true><<<dim3(D_ / 128, M_ / 128), 256, 0, stream>>>(
      src_pair, WqkTp, nullptr, nullptr, qk, qk_b, invn, M_, D_, 2 * D_, 2 * D_, 2 * D_, 0);
  // 2: v projection
  gemm_bf16<1, false, false, false, false><<<dim3(D_ / 128, M_ / 128), 256, 0, stream>>>(
      src_pair, WvT, nullptr, nullptr, nullptr, v_b, nullptr, M_, D_, D_, 2 * D_, D_, 0);
  // 3: LSH buckets (GEMM + fused argmax)
  hash_gemm_kernel<<<dim3(T_ / 128, BH_), 256, 0, stream>>>(qk, rot, buckets);
  // 4-5: counting sort
  hist_kernel<<<BH_, 256, 0, stream>>>(buckets, bstart);
  compact_kernel<<<dim3(256, BH_), 64, 0, stream>>>(buckets, bstart, sticker);
  // 6: chunked attention (MFMA)
  attn_kernel<<<dim3(CHUNKS_, BH_), 256, 0, stream>>>(
      qk_b, v_b, sticker, invn, orows_b, logits);
  // 7: combine hash rounds (writes into qk_b region)
  combine_kernel<<<BH_ * T_ / 4, 256, 0, stream>>>(orows_b, logits, ocomb_b);
  // 8: out projection + bias + residual(src bf16 hi)
  gemm_bf16<1, true, false, true, false><<<dim3(D_ / 128, M_ / 128), 256, 0, stream>>>(
      ocomb_b, WoutT, bout, src_pair, nullptr, x_b, nullptr, M_, D_, D_, D_, D_, 2 * D_);
  // 9: FFN1 (relu)
  gemm_bf16<1, true, true, false, false><<<dim3(FFN_ / 128, M_ / 128), 256, 0, stream>>>(
      x_b, W1T, b1, nullptr, nullptr, hidden_b, nullptr, M_, FFN_, D_, D_, D_, 0);
  // 10: FFN2 + bias + residual(x_b) -> bf16 y
  gemm_bf16<1, true, false, true, false><<<dim3(D_ / 128, M_ / 128), 256, 0, stream>>>(
      hidden_b, W2T, b2, x_b, nullptr, ybuf_b, nullptr, M_, D_, FFN_, FFN_, FFN_, D_);
  // 11: LayerNorm
  ln_kernel<<<M_ / 4, 256, 0, stream>>>(ybuf_b, gamma, beta, out);
}

// Round 6
// 366.238 us; speedup vs baseline: 4.9807x; 1.0594x over previous
//
#include <hip/hip_runtime.h>

#define B_ 4
#define T_ 4096
#define D_ 512
#define H_ 8
#define DH_ 64
#define NH_ 4
#define NB_ 64            // n_buckets = T/BUCKET
#define BH_ (B_*H_)       // 32
#define CHUNKS_ (NH_*NB_) // 256
#define NTICK_ (NH_*T_)   // 16384
#define M_ (B_*T_)        // 16384
#define FFN_ 2048

typedef __attribute__((ext_vector_type(8))) short bf16x8;
typedef __attribute__((ext_vector_type(4))) float f32x4;

// ---------- bf16 helpers (round-to-nearest-even) ----------
__device__ __forceinline__ unsigned short f2bf(float x) {
  unsigned int u = __float_as_uint(x);
  return (unsigned short)((u + 0x7FFFu + ((u >> 16) & 1u)) >> 16);
}
__device__ __forceinline__ float bf2f(unsigned short s) {
  return __uint_as_float(((unsigned int)s) << 16);
}

// ---------- async global->LDS, 16B per lane ----------
__device__ __forceinline__ void gld_lds16(const void* g, void* l) {
  __builtin_amdgcn_global_load_lds(
      (const __attribute__((address_space(1))) unsigned int*)g,
      (__attribute__((address_space(3))) unsigned int*)l, 16, 0, 0);
}

// swizzled LDS offsets (shorts): XOR 16B-granule with row&7 (T2)
__device__ __forceinline__ int off64(int row, int k) {
  return row * 64 + (((k >> 3) ^ (row & 7)) << 3) + (k & 7);
}
__device__ __forceinline__ int off128(int row, int k) {
  return row * 128 + (((k >> 3) ^ (row & 7)) << 3) + (k & 7);
}

// ---------- bf16 MFMA GEMM (m97 structure): C = op(A @ BT^T) ----------
// A: MxK bf16 (stride lda). BT: NxK bf16 (stride ldbt).
// OUT_MODE: 1 = bf16 out (coalesced restage), 2 = + f32 scalar out.
// HAS_RESID: bf16 residual added during coalesced copy-out (stride ldr).
// FUSE_INV: also emit invn[(b*8+head)*T + t] = 1/(||row_head||+1e-6)  (qk only)
template<int OUT_MODE, bool HAS_BIAS, bool RELU, bool HAS_RESID, bool FUSE_INV>
__global__ __launch_bounds__(256) void gemm_bf16(
    const unsigned short* __restrict__ A, const unsigned short* __restrict__ BT,
    const float* __restrict__ bias, const unsigned short* __restrict__ resid,
    float* __restrict__ Cf, unsigned short* __restrict__ Cb,
    float* __restrict__ invn,
    int M, int N, int K, int lda, int ldbt, int ldr)
{
  __shared__ __align__(16) unsigned short smem[2 * 128 * 64];  // As | Bs, then C-tile
  unsigned short* As = smem;
  unsigned short* Bs = smem + 128 * 64;
  const int tid = threadIdx.x;
  const int lane = tid & 63;
  const int w = tid >> 6;
  const int wm = (w >> 1) * 64, wn = (w & 1) * 64;
  const int g = lane >> 4, cl = lane & 15;

  // XCD-aware block swizzle (T1): contiguous linear-id runs per XCD
  const int gx = gridDim.x;
  const int id = blockIdx.x + blockIdx.y * gx;
  const int cpx = (gx * gridDim.y) >> 3;
  const int swz = (id & 7) * cpx + (id >> 3);
  const int m0 = (swz / gx) * 128, n0 = (swz % gx) * 128;

  f32x4 acc[4][4];
#pragma unroll
  for (int i = 0; i < 4; ++i)
#pragma unroll
    for (int j = 0; j < 4; ++j) acc[i][j] = (f32x4){0.f, 0.f, 0.f, 0.f};

  const int srow = tid >> 3;
  const int skc  = (tid & 7) * 8;

  for (int k0 = 0; k0 < K; k0 += 64) {
#pragma unroll
    for (int ci = 0; ci < 4; ++ci) {
      const int row = ci * 32 + srow;
      gld_lds16(&A [(size_t)(m0 + row) * lda  + k0 + skc], &As[ci * 2048 + tid * 8]);
      gld_lds16(&BT[(size_t)(n0 + row) * ldbt + k0 + skc], &Bs[ci * 2048 + tid * 8]);
    }
    __syncthreads();
#pragma unroll
    for (int kk = 0; kk < 64; kk += 32) {
      bf16x8 af[4], bfr[4];
#pragma unroll
      for (int i = 0; i < 4; ++i)
        af[i] = *(const bf16x8*)&As[(wm + i * 16 + cl) * 64 + kk + g * 8];
#pragma unroll
      for (int j = 0; j < 4; ++j)
        bfr[j] = *(const bf16x8*)&Bs[(wn + j * 16 + cl) * 64 + kk + g * 8];
#pragma unroll
      for (int i = 0; i < 4; ++i)
#pragma unroll
        for (int j = 0; j < 4; ++j)
          acc[i][j] = __builtin_amdgcn_mfma_f32_16x16x32_bf16(af[i], bfr[j], acc[i][j], 0, 0, 0);
    }
    __syncthreads();
  }

  // ---- epilogue: bias/relu in regs -> LDS C-tile (swizzled) -> coalesced out
  float bv[4];
  if constexpr (HAS_BIAS) {
#pragma unroll
    for (int j = 0; j < 4; ++j) bv[j] = bias[n0 + wn + j * 16 + cl];
  }
#pragma unroll
  for (int i = 0; i < 4; ++i) {
#pragma unroll
    for (int r = 0; r < 4; ++r) {
      const int lrow = wm + i * 16 + g * 4 + r;
      float ss = 0.f;
#pragma unroll
      for (int j = 0; j < 4; ++j) {
        const int lcol = wn + j * 16 + cl;
        float val = acc[i][j][r];
        if constexpr (HAS_BIAS) val += bv[j];
        if constexpr (RELU) val = fmaxf(val, 0.f);
        if constexpr (FUSE_INV) ss += val * val;
        if constexpr (OUT_MODE == 2) Cf[(size_t)(m0 + lrow) * N + n0 + lcol] = val;
        smem[lrow * 128 + (lcol ^ ((lrow & 7) << 3))] = f2bf(val);
      }
      if constexpr (FUSE_INV) {
        ss += __shfl_xor(ss, 1); ss += __shfl_xor(ss, 2);
        ss += __shfl_xor(ss, 4); ss += __shfl_xor(ss, 8);
        if (cl == 0) {
          const int m = m0 + lrow;
          const int bb = m >> 12, t = m & (T_ - 1);
          const int hh = ((n0 + wn) >> 6) & 7;
          invn[((size_t)(bb * 8 + hh)) * T_ + t] = 1.0f / (sqrtf(ss) + 1e-6f);
        }
      }
    }
  }
  __syncthreads();
#pragma unroll
  for (int l = 0; l < 8; ++l) {
    const int idx = tid + l * 256;
    const int row = idx >> 4, c8 = (idx & 15) * 8;
    uint4 u = *(const uint4*)&smem[row * 128 + (c8 ^ ((row & 7) << 3))];
    if constexpr (HAS_RESID) {
      const uint4 rv = *(const uint4*)&resid[(size_t)(m0 + row) * ldr + n0 + c8];
      unsigned short* sp = (unsigned short*)&u;
      const unsigned short* rp = (const unsigned short*)&rv;
#pragma unroll
      for (int e = 0; e < 8; ++e) sp[e] = f2bf(bf2f(sp[e]) + bf2f(rp[e]));
    }
    *(uint4*)&Cb[(size_t)(m0 + row) * N + n0 + c8] = u;
  }
}

// ---------- fused prep: transpose(+split) 5 weights + split src rows ----------
__global__ __launch_bounds__(256) void prep_all(
    const float* __restrict__ Wqk, const float* __restrict__ Wv,
    const float* __restrict__ Wout, const float* __restrict__ W1,
    const float* __restrict__ W2, const float* __restrict__ src,
    unsigned short* __restrict__ WqkTp, unsigned short* __restrict__ WvT,
    unsigned short* __restrict__ WoutT, unsigned short* __restrict__ W1T,
    unsigned short* __restrict__ W2T, unsigned short* __restrict__ src_pair)
{
  __shared__ float tile[32][33];
  int bid = blockIdx.x;
  if (bid >= 2816) {
    // src split: fp32 row(D) -> bf16 pair row(2D): [hi | lo]
    const int i = (bid - 2816) * 256 + threadIdx.x;    // < M*D/8
    const int gpr = D_ >> 3;
    const int m = i / gpr, d0 = (i - m * gpr) * 8;
    float x[8];
    *(float4*)&x[0] = *(const float4*)&src[(size_t)m * D_ + d0];
    *(float4*)&x[4] = *(const float4*)&src[(size_t)m * D_ + d0 + 4];
    unsigned short hi[8], lo[8];
#pragma unroll
    for (int e = 0; e < 8; ++e) {
      hi[e] = f2bf(x[e]);
      lo[e] = f2bf(x[e] - bf2f(hi[e]));
    }
    *(uint4*)&src_pair[(size_t)m * 2 * D_ + d0]      = *(const uint4*)&hi[0];
    *(uint4*)&src_pair[(size_t)m * 2 * D_ + D_ + d0] = *(const uint4*)&lo[0];
    return;
  }
  const float* W; unsigned short* WT; int K, N, bx, by; bool split = false;
  if (bid < 256)        { W = Wqk;  WT = WqkTp; K = 512;  N = 512;  split = true;
                          bx = bid & 15; by = bid >> 4; }
  else if (bid < 512)   { bid -= 256;  W = Wv;   WT = WvT;   K = 512;  N = 512;
                          bx = bid & 15; by = bid >> 4; }
  else if (bid < 768)   { bid -= 512;  W = Wout; WT = WoutT; K = 512;  N = 512;
                          bx = bid & 15; by = bid >> 4; }
  else if (bid < 1792)  { bid -= 768;  W = W1;   WT = W1T;   K = 512;  N = 2048;
                          bx = bid & 63; by = bid >> 6; }
  else                  { bid -= 1792; W = W2;   WT = W2T;   K = 2048; N = 512;
                          bx = bid & 15; by = bid >> 4; }
  const int k0 = by * 32, n0 = bx * 32;
  const int tx = threadIdx.x & 31, ty = threadIdx.x >> 5;
#pragma unroll
  for (int r = 0; r < 32; r += 8)
    tile[ty + r][tx] = W[(size_t)(k0 + ty + r) * N + n0 + tx];
  __syncthreads();
  const int ld = split ? 2 * K : K;
#pragma unroll
  for (int r = 0; r < 32; r += 8) {
    const float x = tile[tx][ty + r];
    const unsigned short hi = f2bf(x);
    WT[(size_t)(n0 + ty + r) * ld + k0 + tx] = hi;
    if (split)
      WT[(size_t)(n0 + ty + r) * ld + K + k0 + tx] = f2bf(x - bf2f(hi));
  }
}

// ---------- LSH hashing as GEMM + fused argmax (reads fp32 qk) ----------
__global__ __launch_bounds__(256) void hash_gemm_kernel(
    const float* __restrict__ qk, const float* __restrict__ rot,
    int* __restrict__ buckets)
{
  __shared__ __align__(16) float As[64][136];   // [k][m]
  __shared__ __align__(16) float Bs[64][132];   // [k][n]
  const int tid = threadIdx.x;
  const int tx = tid & 15, ty = tid >> 4;
  const int t0 = blockIdx.x * 128, bh = blockIdx.y;
  const int b = bh >> 3, hd = bh & 7;

#pragma unroll
  for (int l = 0; l < 8; ++l) {
    const int idx = tid + l * 256;
    const int row = idx >> 4;
    const int kq = (idx & 15) << 2;
    const float4 a = *(const float4*)&qk[((size_t)b * T_ + t0 + row) * D_ + hd * DH_ + kq];
    As[kq + 0][row] = a.x; As[kq + 1][row] = a.y;
    As[kq + 2][row] = a.z; As[kq + 3][row] = a.w;
  }
#pragma unroll
  for (int l = 0; l < 8; ++l) {
    const int idx = tid + l * 256;
    const int kr = idx >> 5;
    const int c4 = (idx & 31) << 2;
    *(float4*)&Bs[kr][c4] = *(const float4*)&rot[kr * 128 + c4];
  }
  __syncthreads();

  float acc[8][8];
#pragma unroll
  for (int i = 0; i < 8; ++i)
#pragma unroll
    for (int j = 0; j < 8; ++j) acc[i][j] = 0.f;

#pragma unroll 4
  for (int kk = 0; kk < 64; ++kk) {
    float a[8], bq[8];
    *(float4*)&a[0]  = *(const float4*)&As[kk][ty * 8];
    *(float4*)&a[4]  = *(const float4*)&As[kk][ty * 8 + 4];
    *(float4*)&bq[0] = *(const float4*)&Bs[kk][tx * 8];
    *(float4*)&bq[4] = *(const float4*)&Bs[kk][tx * 8 + 4];
#pragma unroll
    for (int i = 0; i < 8; ++i)
#pragma unroll
      for (int j = 0; j < 8; ++j)
        acc[i][j] = fmaf(a[i], bq[j], acc[i][j]);
  }
  __syncthreads();

  float* pval = &As[0][0];
  int*   pidx = (int*)&Bs[0][0];
  const int i0 = (tx & 3) * 8;
#pragma unroll
  for (int r = 0; r < 8; ++r) {
    float v = -3.0e38f; int idx = 127;
#pragma unroll
    for (int j = 0; j < 8; ++j) {
      const float p = acc[r][j];
      const int li = i0 + j;
      if (p > v || (p == v && li < idx)) { v = p; idx = li; }
      const float n = -p;
      const int ni = 32 + li;
      if (n > v || (n == v && ni < idx)) { v = n; idx = ni; }
    }
    pval[(ty * 8 + r) * 16 + tx] = v;
    pidx[(ty * 8 + r) * 16 + tx] = idx;
  }
  __syncthreads();

#pragma unroll
  for (int l = 0; l < 2; ++l) {
    const int id = tid + l * 256;
    const int tok = id >> 2, hh = id & 3;
    float v = pval[tok * 16 + hh * 4];
    int idx = pidx[tok * 16 + hh * 4];
#pragma unroll
    for (int e = 1; e < 4; ++e) {
      const float ov = pval[tok * 16 + hh * 4 + e];
      const int oi = pidx[tok * 16 + hh * 4 + e];
      if (ov > v || (ov == v && oi < idx)) { v = ov; idx = oi; }
    }
    buckets[((size_t)bh * NH_ + hh) * T_ + t0 + tok] = idx + hh * NB_;
  }
}

// ---------- per-bh bucket histogram + exclusive scan ----------
__global__ __launch_bounds__(256) void hist_kernel(
    const int* __restrict__ buckets, int* __restrict__ bstart)
{
  __shared__ int bins[256];
  const int bh = blockIdx.x;
  bins[threadIdx.x] = 0;
  __syncthreads();
  for (int e = threadIdx.x; e < NTICK_; e += 256)
    atomicAdd(&bins[buckets[(size_t)bh * NTICK_ + e]], 1);
  __syncthreads();
  if (threadIdx.x == 0) {
    int run = 0;
    for (int i = 0; i < 256; ++i) { const int c = bins[i]; bins[i] = run; run += c; }
  }
  __syncthreads();
  bstart[bh * 256 + threadIdx.x] = bins[threadIdx.x];
}

// ---------- stable compaction ----------
__global__ __launch_bounds__(64) void compact_kernel(
    const int* __restrict__ buckets, const int* __restrict__ bstart,
    int* __restrict__ sticker)
{
  const int bucket = blockIdx.x, bh = blockIdx.y;
  const int h = bucket >> 6;
  const int lane = threadIdx.x;
  int base = bstart[bh * 256 + bucket];
  const int* bk = buckets + (size_t)bh * NTICK_ + (size_t)h * T_;
  for (int it = 0; it < 64; ++it) {
    const int t = it * 64 + lane;
    const bool m = (bk[t] == bucket);
    const unsigned long long bal = __ballot(m);
    if (m) {
      const int pos = base + __popcll(bal & ((1ull << lane) - 1ull));
      sticker[(size_t)bh * NTICK_ + pos] = h * T_ + t;
    }
    base += __popcll(bal);
  }
}

// ---------- chunked LSH attention — MFMA, 33 KB LDS ----------
// Rs: qk rows -> P (unnormalized) -> O.  Vs: v rows -> V^T (in place).
// Skip-max softmax: |dots| <= |q|/8 (small), so exp without max-subtract is
// safe; masked key contributes exactly 0 (matches exp(-5e4 - lse)).
// orows layout: [bh][t][hr][dh]; logits: [bh][t][hr].
__global__ __launch_bounds__(256) void attn_kernel(
    const unsigned short* __restrict__ qkb, const unsigned short* __restrict__ vb,
    const int* __restrict__ sticker, const float* __restrict__ invn,
    unsigned short* __restrict__ orowsb, float* __restrict__ logits)
{
  __shared__ __align__(16) unsigned short Rs[128 * 64];
  __shared__ __align__(16) unsigned short Vs[128 * 64];
  __shared__ int tks[128];
  __shared__ float invs[128];

  // XCD-aware chunk swizzle: chunks [k*32, k*32+32) on XCD k (bijective, 256=8*32)
  const int cx = blockIdx.x;
  const int c = (cx & 7) * 32 + (cx >> 3);
  const int bh = blockIdx.y;
  const int b = bh >> 3, hd = bh & 7;
  const int tid = threadIdx.x;
  const int hr = c >> 6;
  const int w = tid >> 6, lane = tid & 63, g = lane >> 4, cl = lane & 15;

  if (tid < 128) {
    const int sc = (tid < 64) ? c : ((c + CHUNKS_ - 1) & (CHUNKS_ - 1));
    const int tick = sticker[(size_t)bh * NTICK_ + sc * 64 + (tid & 63)];
    const int t = tick & (T_ - 1);
    tks[tid] = t;
    invs[tid] = invn[bh * T_ + t];
  }
  __syncthreads();

  // stage qk + v rows (bf16), swizzled
#pragma unroll
  for (int l = 0; l < 4; ++l) {
    const int idx = tid + l * 256;
    const int row = idx >> 3, k0 = (idx & 7) * 8;
    const size_t gb = ((size_t)b * T_ + tks[row]) * D_ + hd * DH_ + k0;
    *(uint4*)&Rs[off64(row, k0)] = *(const uint4*)&qkb[gb];
    *(uint4*)&Vs[off64(row, k0)] = *(const uint4*)&vb[gb];
  }
  __syncthreads();

  // dots (MFMA from Rs) + V transpose-read (b64) into regs
  f32x4 sacc[8];
#pragma unroll
  for (int j = 0; j < 8; ++j) sacc[j] = (f32x4){0.f, 0.f, 0.f, 0.f};
#pragma unroll
  for (int kk = 0; kk < 2; ++kk) {
    const bf16x8 aq = *(const bf16x8*)&Rs[off64(w * 16 + cl, kk * 32 + g * 8)];
#pragma unroll
    for (int j = 0; j < 8; ++j) {
      const bf16x8 bk = *(const bf16x8*)&Rs[off64(j * 16 + cl, kk * 32 + g * 8)];
      sacc[j] = __builtin_amdgcn_mfma_f32_16x16x32_bf16(aq, bk, sacc[j], 0, 0, 0);
    }
  }
  // thread owns d-quad d0..d0+3 x tokens tg*8..+7
  const int d0 = (tid & 15) * 4, tg = tid >> 4;
  unsigned int qw[8][2];
#pragma unroll
  for (int e = 0; e < 8; ++e) {
    const uint2 q = *(const uint2*)&Vs[off64(tg * 8 + e, d0)];
    qw[e][0] = q.x; qw[e][1] = q.y;
  }
  __syncthreads();

  // write V^T into Vs region; softmax from sacc -> unnormalized P into Rs
  {
    unsigned short col[4][8];
#pragma unroll
    for (int e = 0; e < 8; ++e) {
      col[0][e] = (unsigned short)(qw[e][0] & 0xffffu);
      col[1][e] = (unsigned short)(qw[e][0] >> 16);
      col[2][e] = (unsigned short)(qw[e][1] & 0xffffu);
      col[3][e] = (unsigned short)(qw[e][1] >> 16);
    }
#pragma unroll
    for (int dd = 0; dd < 4; ++dd)
      *(uint4*)&Vs[off128(d0 + dd, tg * 8)] = *(const uint4*)&col[dd][0];
  }

  float iv[8]; int tk[8];
#pragma unroll
  for (int j = 0; j < 8; ++j) {
    iv[j] = invs[j * 16 + cl] * 0.125f;
    tk[j] = tks[j * 16 + cl];
  }
  float pinv[4];
#pragma unroll
  for (int r = 0; r < 4; ++r) {
    const int row = w * 16 + g * 4 + r;
    const int tq = tks[row];
    float e8[8];
    float sum = 0.f;
#pragma unroll
    for (int j = 0; j < 8; ++j) {
      float e = __expf(sacc[j][r] * iv[j]);
      if (tq == tk[j]) e = 0.f;
      e8[j] = e;
      sum += e;
    }
    sum += __shfl_xor(sum, 1); sum += __shfl_xor(sum, 2);
    sum += __shfl_xor(sum, 4); sum += __shfl_xor(sum, 8);
    pinv[r] = 1.f / sum;
#pragma unroll
    for (int j = 0; j < 8; ++j)
      Rs[off128(row, j * 16 + cl)] = f2bf(e8[j]);       // unnormalized
    if (cl == 0)
      logits[((size_t)bh * T_ + tq) * NH_ + hr] = __logf(sum);
  }
  __syncthreads();

  // PV: A = P (Rs), B = V^T (Vs)
  f32x4 oacc[4];
#pragma unroll
  for (int jd = 0; jd < 4; ++jd) oacc[jd] = (f32x4){0.f, 0.f, 0.f, 0.f};
#pragma unroll
  for (int ks = 0; ks < 4; ++ks) {
    const bf16x8 pa = *(const bf16x8*)&Rs[off128(w * 16 + cl, ks * 32 + g * 8)];
#pragma unroll
    for (int jd = 0; jd < 4; ++jd) {
      const bf16x8 vv = *(const bf16x8*)&Vs[off128(jd * 16 + cl, ks * 32 + g * 8)];
      oacc[jd] = __builtin_amdgcn_mfma_f32_16x16x32_bf16(pa, vv, oacc[jd], 0, 0, 0);
    }
  }
  __syncthreads();   // P fully consumed across waves before O overwrites Rs

  // O (scaled by 1/sum) into Rs, then coalesced scatter to global
#pragma unroll
  for (int jd = 0; jd < 4; ++jd)
#pragma unroll
    for (int r = 0; r < 4; ++r)
      Rs[off64(w * 16 + g * 4 + r, jd * 16 + cl)] = f2bf(oacc[jd][r] * pinv[r]);
  __syncthreads();

#pragma unroll
  for (int l = 0; l < 2; ++l) {
    const int idx = tid + l * 256;
    const int row = idx >> 3, k0 = (idx & 7) * 8;
    *(uint4*)&orowsb[(((size_t)bh * T_ + tks[row]) * NH_ + hr) * DH_ + k0] =
        *(const uint4*)&Rs[off64(row, k0)];
  }
}

// ---------- combine hash rounds (contiguous per-token layout) ----------
__global__ __launch_bounds__(256) void combine_kernel(
    const unsigned short* __restrict__ orowsb, const float* __restrict__ logits,
    unsigned short* __restrict__ ocombb)
{
  const int gid = blockIdx.x * 4 + (threadIdx.x >> 6);
  const int lane = threadIdx.x & 63;
  const int bh = gid >> 12, t = gid & (T_ - 1);
  const int b = bh >> 3, hd = bh & 7;
  const float4 lg = *(const float4*)&logits[((size_t)bh * T_ + t) * NH_];
  const float m = fmaxf(fmaxf(lg.x, lg.y), fmaxf(lg.z, lg.w));
  const float w0 = __expf(lg.x - m), w1 = __expf(lg.y - m);
  const float w2 = __expf(lg.z - m), w3 = __expf(lg.w - m);
  const float inv = 1.f / (w0 + w1 + w2 + w3);
  const size_t rb = ((size_t)bh * T_ + t) * (NH_ * DH_) + lane;
  const float o = w0 * bf2f(orowsb[rb])
                + w1 * bf2f(orowsb[rb + DH_])
                + w2 * bf2f(orowsb[rb + 2 * DH_])
                + w3 * bf2f(orowsb[rb + 3 * DH_]);
  ocombb[((size_t)b * T_ + t) * D_ + hd * DH_ + lane] = f2bf(o * inv);
}

// ---------- LayerNorm (bf16 in, fp32 out) ----------
__global__ __launch_bounds__(256) void ln_kernel(
    const unsigned short* __restrict__ yb, const float* __restrict__ gamma,
    const float* __restrict__ beta, float* __restrict__ out)
{
  const int row = blockIdx.x * 4 + (threadIdx.x >> 6);
  const int lane = threadIdx.x & 63;
  const size_t base = (size_t)row * D_ + lane * 8;
  const uint4 u = *(const uint4*)&yb[base];
  const unsigned short* up = (const unsigned short*)&u;
  float x[8];
#pragma unroll
  for (int i = 0; i < 8; ++i) x[i] = bf2f(up[i]);
  float s = 0.f;
#pragma unroll
  for (int i = 0; i < 8; ++i) s += x[i];
#pragma unroll
  for (int m = 32; m >= 1; m >>= 1) s += __shfl_xor(s, m);
  const float mu = s * (1.f / D_);
  float vs = 0.f;
#pragma unroll
  for (int i = 0; i < 8; ++i) { const float d = x[i] - mu; vs += d * d; }
#pragma unroll
  for (int m = 32; m >= 1; m >>= 1) vs += __shfl_xor(vs, m);
  const float rstd = rsqrtf(vs * (1.f / D_) + 1e-6f);
  float gm[8], bt[8];
  *(float4*)&gm[0] = *(const float4*)&gamma[lane * 8];
  *(float4*)&gm[4] = *(const float4*)&gamma[lane * 8 + 4];
  *(float4*)&bt[0] = *(const float4*)&beta[lane * 8];
  *(float4*)&bt[4] = *(const float4*)&beta[lane * 8 + 4];
  float o[8];
#pragma unroll
  for (int i = 0; i < 8; ++i) o[i] = (x[i] - mu) * rstd * gm[i] + bt[i];
  *(float4*)&out[base]     = make_float4(o[0], o[1], o[2], o[3]);
  *(float4*)&out[base + 4] = make_float4(o[4], o[5], o[6], o[7]);
}

extern "C" void kernel_launch(void* const* d_in, const int* in_sizes, int n_in,
                              void* d_out, int out_size, void* d_ws, size_t ws_size,
                              hipStream_t stream) {
  (void)in_sizes; (void)n_in; (void)out_size; (void)ws_size;
  const float* src   = (const float*)d_in[0];
  const float* Wqk   = (const float*)d_in[1];
  const float* Wv    = (const float*)d_in[2];
  const float* Wout  = (const float*)d_in[3];
  const float* bout  = (const float*)d_in[4];
  const float* W1    = (const float*)d_in[5];
  const float* b1    = (const float*)d_in[6];
  const float* W2    = (const float*)d_in[7];
  const float* b2    = (const float*)d_in[8];
  const float* gamma = (const float*)d_in[9];
  const float* beta  = (const float*)d_in[10];
  const float* rot   = (const float*)d_in[11];
  float* out = (float*)d_out;

  // ---- workspace layout ----
  char* ws = (char*)d_ws;
  const size_t MB = 1024 * 1024;
  float*          qk       = (float*)(ws);                     // 32 MB; dead after hash
  unsigned short* src_pair = (unsigned short*)(ws + 32 * MB);  // 32 MB [hi|lo]; live thru Wout
  unsigned short* v_b      = (unsigned short*)(ws + 64 * MB);  // 16 MB; -> x_b after attn
  unsigned short* orows_b  = (unsigned short*)(ws + 80 * MB);  // 64 MB; -> hidden_b
  unsigned short* qk_b     = (unsigned short*)(ws + 144 * MB); // 16 MB; -> ocomb_b after attn
  char* p = ws + 160 * MB;
  float* logits  = (float*)p; p += (size_t)BH_ * NH_ * T_ * 4;
  int*   buckets = (int*)p;   p += (size_t)BH_ * NH_ * T_ * 4;
  int*   sticker = (int*)p;   p += (size_t)BH_ * NTICK_ * 4;
  int*   bstart  = (int*)p;   p += (size_t)BH_ * 256 * 4;
  float* invn    = (float*)p; p += (size_t)BH_ * T_ * 4;
  unsigned short* WvT    = (unsigned short*)p; p += (size_t)D_ * D_ * 2;
  unsigned short* WoutT  = (unsigned short*)p; p += (size_t)D_ * D_ * 2;
  unsigned short* W1T    = (unsigned short*)p; p += (size_t)FFN_ * D_ * 2;
  unsigned short* W2T    = (unsigned short*)p; p += (size_t)D_ * FFN_ * 2;
  unsigned short* WqkTp  = (unsigned short*)p; p += (size_t)D_ * 2 * D_ * 2;

  unsigned short* ocomb_b  = qk_b;                 // after attn consumed qk_b
  unsigned short* x_b      = v_b;                  // after attn consumed v_b
  unsigned short* hidden_b = orows_b;              // after combine consumed orows
  unsigned short* ybuf_b   = (unsigned short*)ws;  // after hash consumed qk f32

  // 0: all conversions in one launch (weights + src split)
  prep_all<<<2816 + M_ * D_ / 8 / 256, 256, 0, stream>>>(
      Wqk, Wv, Wout, W1, W2, src, WqkTp, WvT, WoutT, W1T, W2T, src_pair);

  // 1: qk projection — split-bf16 MFMA (K=1024, fp32-exact) + fused invnorm
  gemm_bf16<2, false, false, false, true><<<dim3(D_ / 128, M_ / 128), 256, 0, stream>>>(
      src_pair, WqkTp, nullptr, nullptr, qk, qk_b, invn, M_, D_, 2 * D_, 2 * D_, 2 * D_, 0);
  // 2: v projection
  gemm_bf16<1, false, false, false, false><<<dim3(D_ / 128, M_ / 128), 256, 0, stream>>>(
      src_pair, WvT, nullptr, nullptr, nullptr, v_b, nullptr, M_, D_, D_, 2 * D_, D_, 0);
  // 3: LSH buckets (GEMM + fused argmax)
  hash_gemm_kernel<<<dim3(T_ / 128, BH_), 256, 0, stream>>>(qk, rot, buckets);
  // 4-5: counting sort
  hist_kernel<<<BH_, 256, 0, stream>>>(buckets, bstart);
  compact_kernel<<<dim3(256, BH_), 64, 0, stream>>>(buckets, bstart, sticker);
  // 6: chunked attention (MFMA)
  attn_kernel<<<dim3(CHUNKS_, BH_), 256, 0, stream>>>(
      qk_b, v_b, sticker, invn, orows_b, logits);
  // 7: combine hash rounds (writes into qk_b region)
  combine_kernel<<<BH_ * T_ / 4, 256, 0, stream>>>(orows_b, logits, ocomb_b);
  // 8: out projection + bias + residual(src bf16 hi)
  gemm_bf16<1, true, false, true, false><<<dim3(D_ / 128, M_ / 128), 256, 0, stream>>>(
      ocomb_b, WoutT, bout, src_pair, nullptr, x_b, nullptr, M_, D_, D_, D_, D_, 2 * D_);
  // 9: FFN1 (relu)
  gemm_bf16<1, true, true, false, false><<<dim3(FFN_ / 128, M_ / 128), 256, 0, stream>>>(
      x_b, W1T, b1, nullptr, nullptr, hidden_b, nullptr, M_, FFN_, D_, D_, D_, 0);
  // 10: FFN2 + bias + residual(x_b) -> bf16 y
  gemm_bf16<1, true, false, true, false><<<dim3(D_ / 128, M_ / 128), 256, 0, stream>>>(
      hidden_b, W2T, b2, x_b, nullptr, ybuf_b, nullptr, M_, D_, FFN_, FFN_, FFN_, D_);
  // 11: LayerNorm
  ln_kernel<<<M_ / 4, 256, 0, stream>>>(ybuf_b, gamma, beta, out);
}